// Round 10
// baseline (258.636 us; speedup 1.0000x reference)
//
#include <hip/hip_runtime.h>
#include <hip/hip_bf16.h>

typedef unsigned short ushort_t;
typedef __bf16 bf16x8 __attribute__((ext_vector_type(8)));
typedef float f32x4 __attribute__((ext_vector_type(4)));

// Problem constants
#define E_TOT 16896
#define NT    1536
#define BGR   128
#define NPG   12
#define EPG   132
#define KD    192    // DIM_E + DIM_U
#define KDE   128    // DIM_E only (GEMM K after cg-folding)
#define KD2   384    // split-K over ef: [hi | lo | hi] x [hi | hi | lo]
#define NJ    512    // A*MID
#define NCAN  8448   // canonical edge pairs (s<d): 128 * 66

#if defined(__has_builtin)
#  if __has_builtin(__builtin_amdgcn_global_load_lds)
#    define HAS_GLL 1
#  else
#    define HAS_GLL 0
#  endif
#else
#  define HAS_GLL 0
#endif

#if HAS_GLL
__device__ __forceinline__ void gll16(const ushort_t* g, ushort_t* s) {
    __builtin_amdgcn_global_load_lds(
        (const __attribute__((address_space(1))) unsigned int*)g,
        (__attribute__((address_space(3))) unsigned int*)s, 16, 0, 0);
}
#endif

__device__ __forceinline__ float b2f(ushort_t u) {
    union { float f; unsigned int i; } c; c.i = ((unsigned int)u) << 16; return c.f;
}
__device__ __forceinline__ ushort_t f2b(float f) {
    union { float f; unsigned int i; } c; c.f = f;
    unsigned int i = c.i;
    unsigned int r = (i + 0x7FFFu + ((i >> 16) & 1u)) >> 16;
    return (ushort_t)r;
}
// fully-connected graph: local edge i=(s->d), s=i/11, d with s-skip.
__device__ __forceinline__ int rev_local(int i) {
    int s = i / 11;
    int p = i - 11 * s;
    int d = p + (p >= s ? 1 : 0);
    return d * 11 + (s < d ? s : s - 1);
}

// ---------------------------------------------------------------------------
// prep v2 — coalesced (unchanged).
// ---------------------------------------------------------------------------
__global__ __launch_bounds__(256) void prep_kernel(
    const float* __restrict__ Wjf, const float* __restrict__ Wju,
    const float* __restrict__ ef,  const float* __restrict__ gf,
    const float* __restrict__ bjf, const float* __restrict__ bju,
    const float* __restrict__ nf,
    const float* __restrict__ Wif, const float* __restrict__ bif,
    const float* __restrict__ Wiu, const float* __restrict__ biu,
    ushort_t* __restrict__ WtJFs, ushort_t* __restrict__ WtJUs,
    ushort_t* __restrict__ XeS, float* __restrict__ CG,
    float* __restrict__ IFF, float* __restrict__ IUU)
{
    __shared__ union {
        float tile[64][65];                      // 16.6 KB (transpose)
        struct { float Ws[128 * 32]; float xr[8][128]; } nd;   // 20 KB (node)
    } sm;
    int tid = threadIdx.x;
    unsigned bx = blockIdx.x;

    if (bx < 32u) {
        // ---- W transpose: mat (0=jf,1=ju), 64k x 64n tile ----
        int mat = bx >> 4, t16 = bx & 15;
        int k0 = (t16 >> 3) * 64, n0 = (t16 & 7) * 64;
        const float* W = mat ? Wju : Wjf;
        ushort_t* Wt = mat ? WtJUs : WtJFs;
        int col = tid & 63, rowq = tid >> 6;
#pragma unroll
        for (int i = 0; i < 16; ++i) {
            int kk = i * 4 + rowq;
            sm.tile[kk][col] = W[(size_t)(k0 + kk) * NJ + n0 + col];
        }
        __syncthreads();
        int k = tid & 63;
#pragma unroll
        for (int i = 0; i < 16; ++i) {
            int nn = i * 4 + rowq;
            float wf = sm.tile[k][nn];
            ushort_t hf = f2b(wf);
            ushort_t lo = f2b(wf - b2f(hf));
            ushort_t* dst = Wt + (size_t)(n0 + nn) * KD2 + k0 + k;
            dst[0]   = hf;
            dst[128] = hf;
            dst[256] = lo;
        }
        return;
    }
    if (bx < 1088u) {
        // ---- XeS: thread = (e, k8) handles 8 k's ----
        int t = (int)(bx - 32u) * 256 + tid;
        int e = t >> 4, k8 = t & 15;
        const float* src = ef + (size_t)e * KDE + k8 * 8;
        float4 v0 = *(const float4*)(src);
        float4 v1 = *(const float4*)(src + 4);
        float x[8] = { v0.x, v0.y, v0.z, v0.w, v1.x, v1.y, v1.z, v1.w };
        union { ushort_t u[8]; uint4 v; } hi, lo;
#pragma unroll
        for (int i = 0; i < 8; ++i) {
            ushort_t h = f2b(x[i]);
            hi.u[i] = h;
            lo.u[i] = f2b(x[i] - b2f(h));
        }
        ushort_t* dst = XeS + (size_t)e * KD2 + k8 * 8;
        *(uint4*)(dst)       = hi.v;
        *(uint4*)(dst + 128) = lo.v;
        *(uint4*)(dst + 256) = hi.v;
        return;
    }
    if (bx < 1600u) {
        // ---- cg: cidx = z*65536 + g*512 + n ----
        int cidx = (int)(bx - 1088u) * 256 + tid;
        int z = cidx >> 16;
        int rem = cidx & 65535;
        int g = rem >> 9, n = rem & 511;
        const float* W = z ? Wju : Wjf;
        float acc = (z ? bju : bjf)[n];
        const float* gr = gf + g * 64;
#pragma unroll 8
        for (int k = 0; k < 64; ++k)
            acc += gr[k] * W[(size_t)(KDE + k) * NJ + n];
        CG[cidx] = acc;
        return;
    }
    // ---- node linear: 8 nodes per block ----
    int n0 = (int)(bx - 1600u) * 8;
    for (int i = tid; i < 128 * 32; i += 256) {
        int k = i >> 5, j = i & 31;
        sm.nd.Ws[i] = (j < 16) ? Wif[k * 16 + j] : Wiu[k * 16 + (j - 16)];
    }
    for (int i = tid; i < 8 * 128; i += 256) {
        int slot = i >> 7, k = i & 127;
        int n = n0 + slot;
        sm.nd.xr[slot][k] = (k < 64) ? nf[(size_t)n * 64 + k]
                                     : gf[(n / NPG) * 64 + (k - 64)];
    }
    __syncthreads();
    int slot = tid >> 5, j = tid & 31;
    float acc = (j < 16) ? bif[j] : biu[j - 16];
#pragma unroll 8
    for (int k = 0; k < 128; ++k) acc += sm.nd.xr[slot][k] * sm.nd.Ws[k * 32 + j];
    int n = n0 + slot;
    if (j < 16) IFF[n * 16 + j] = acc;
    else        IUU[n * 16 + (j - 16)] = acc;
}

// ---------------------------------------------------------------------------
// gp_kernel (R21): fused GEMM+pair — H2 eliminated.
// Block = 16 canonical pairs (32 edge rows), one z.  Grid (528, 2).
//  Phase 1: M=32 x N=512 x K=384 GEMM into LDS Hs (fp32, padded cols:
//           pc = c + (c>>5)*4 -> each 32-col group starts at 36-word stride,
//           16B aligned, b-group reads land on distinct banks).
//           Same K-step order + fragments as the old gemm -> H bits exact.
//  Phase 2: per-element cg add (same operands/order as old pair — exact).
//  Phase 3: pair einsum copied verbatim from old pair, reading Hs.
// ---------------------------------------------------------------------------
#define HPAD 576   // 512 + 16 groups * 4 pad words

__global__ __launch_bounds__(256) void gp_kernel(
    const ushort_t* __restrict__ X,
    const ushort_t* __restrict__ Wt0, const ushort_t* __restrict__ Wt1,
    const float* __restrict__ CG, float* __restrict__ Obase_all)
{
    __shared__ float Hs[32 * HPAD];          // 73.7 KB
    __shared__ ushort_t As[2][32][32];       // 4 KB
    __shared__ ushort_t Bs[2][128][32];      // 16 KB
    __shared__ float sC[4][16][20];          // 5 KB
    __shared__ int eid[32];

    int tid = threadIdx.x, lane = tid & 63, w = tid >> 6;
    int z = blockIdx.y;
    const ushort_t* Wt = z ? Wt1 : Wt0;
    const float* cgz = CG + (size_t)z * 128 * NJ;
    float* OutV = Obase_all + (size_t)z * E_TOT * 256;

    if (tid < 16) {
        int c = blockIdx.x * 16 + tid;
        int gg = c / 66, cl = c - gg * 66;
        int s = 0;
        while (cl >= 11 - s) { cl -= 11 - s; ++s; }
        int d = s + 1 + cl;                  // s < d
        eid[2 * tid]     = gg * EPG + s * 11 + (d - 1);   // edge s->d
        eid[2 * tid + 1] = gg * EPG + d * 11 + s;         // edge d->s
    }
    __syncthreads();

    // staging addresses (B mirrors the old gemm exactly)
    int sr = w * 32 + (lane >> 2);
    int sc = (lane & 3) * 8;
    int achunk = w * 64 + lane;              // A staged by waves 0,1
    int arow = achunk >> 2;
    int asc = (achunk & 3) * 8;
    const ushort_t* ag = X;                  // safe default
    if (w < 2) ag = X + (size_t)eid[arow] * KD2 + asc;

    int r = lane & 15, q = lane >> 4;

    for (int nc = 0; nc < 4; ++nc) {
        int n0g = nc * 128;
        const ushort_t* wg0 = Wt + (size_t)(n0g + sr) * KD2 + sc;
        const ushort_t* wg1 = Wt + (size_t)(n0g + sr + 16) * KD2 + sc;
#if HAS_GLL
        auto stage = [&](int p, int kk) {
            gll16(wg0 + kk, &Bs[p][w * 32][0]);
            gll16(wg1 + kk, &Bs[p][w * 32 + 16][0]);
            if (w < 2) gll16(ag + kk, &As[p][w * 16][0]);
        };
#else
        auto stage = [&](int p, int kk) {
            uint4 b0 = *(const uint4*)(wg0 + kk);
            uint4 b1 = *(const uint4*)(wg1 + kk);
            *(uint4*)&Bs[p][sr][sc]      = b0;
            *(uint4*)&Bs[p][sr + 16][sc] = b1;
            if (w < 2) {
                uint4 a0v = *(const uint4*)(ag + kk);
                *(uint4*)&As[p][arow][asc] = a0v;
            }
        };
#endif
        f32x4 acc[2][2] = {};
        stage(0, 0);
        int cur = 0;
        for (int kk = 0; kk < KD2; kk += 32) {
            __syncthreads();
            if (kk + 32 < KD2) stage(cur ^ 1, kk + 32);
            bf16x8 af[2], bf[2];
            af[0] = *(const bf16x8*)&As[cur][r][q * 8];
            af[1] = *(const bf16x8*)&As[cur][16 + r][q * 8];
            bf[0] = *(const bf16x8*)&Bs[cur][w * 32 + r][q * 8];
            bf[1] = *(const bf16x8*)&Bs[cur][w * 32 + 16 + r][q * 8];
#pragma unroll
            for (int mi = 0; mi < 2; ++mi)
#pragma unroll
                for (int ni = 0; ni < 2; ++ni)
                    acc[mi][ni] = __builtin_amdgcn_mfma_f32_16x16x32_bf16(
                        af[mi], bf[ni], acc[mi][ni], 0, 0, 0);
            cur ^= 1;
        }
        // epilogue: acc -> Hs (padded).  group = (n0g + w*32)>>5 = nc*4 + w.
        int pcoff = (nc * 4 + w) * 4;
#pragma unroll
        for (int ni = 0; ni < 2; ++ni) {
            int col = n0g + w * 32 + ni * 16 + r;
            int pc = col + pcoff;
#pragma unroll
            for (int mi = 0; mi < 2; ++mi) {
                int rowb = mi * 16 + q * 4;
#pragma unroll
                for (int rr = 0; rr < 4; ++rr)
                    Hs[(rowb + rr) * HPAD + pc] = acc[mi][ni][rr];
            }
        }
        __syncthreads();   // tiles free for next nc; Hs visible later
    }

    // ---- cg add (exact: same per-element fp32 add as old pair) ----
    {
        int rowL = tid >> 3;
        int c0 = (tid & 7) * 64;
        int ge = eid[rowL] / EPG;
        const float* cgr = cgz + (size_t)ge * NJ;
        float* hrow = &Hs[rowL * HPAD];
#pragma unroll
        for (int i = 0; i < 16; ++i) {
            int c = c0 + i * 4;
            int pc = c + (c >> 5) * 4;
            float4 h = *(float4*)&hrow[pc];
            float4 cgv = *(const float4*)&cgr[c];
            h.x += cgv.x; h.y += cgv.y; h.z += cgv.z; h.w += cgv.w;
            *(float4*)&hrow[pc] = h;
        }
    }
    __syncthreads();

    // ---- pair einsum (verbatim structure from old pair_kernel) ----
    int b = lane & 15, a0 = (lane >> 4) * 4;
    for (int pi = 0; pi < 4; ++pi) {
        int p = w * 4 + pi;
        const float* hA = &Hs[(2 * p) * HPAD];
        const float* hB = &Hs[(2 * p + 1) * HPAD];
        float4 ac0 = {0,0,0,0}, ac1 = {0,0,0,0}, ac2 = {0,0,0,0}, ac3 = {0,0,0,0};
#pragma unroll
        for (int m4 = 0; m4 < 8; ++m4) {
            float4 vb = *(const float4*)&hB[b * 36 + m4 * 4];
            float4 x0 = *(const float4*)&hA[(a0 + 0) * 36 + m4 * 4];
            float4 x1 = *(const float4*)&hA[(a0 + 1) * 36 + m4 * 4];
            float4 x2 = *(const float4*)&hA[(a0 + 2) * 36 + m4 * 4];
            float4 x3 = *(const float4*)&hA[(a0 + 3) * 36 + m4 * 4];
            ac0.x += x0.x * vb.x; ac0.y += x0.y * vb.y; ac0.z += x0.z * vb.z; ac0.w += x0.w * vb.w;
            ac1.x += x1.x * vb.x; ac1.y += x1.y * vb.y; ac1.z += x1.z * vb.z; ac1.w += x1.w * vb.w;
            ac2.x += x2.x * vb.x; ac2.y += x2.y * vb.y; ac2.z += x2.z * vb.z; ac2.w += x2.w * vb.w;
            ac3.x += x3.x * vb.x; ac3.y += x3.y * vb.y; ac3.z += x3.z * vb.z; ac3.w += x3.w * vb.w;
        }
        float v0 = ac0.x + ac0.y + ac0.z + ac0.w;
        float v1 = ac1.x + ac1.y + ac1.z + ac1.w;
        float v2 = ac2.x + ac2.y + ac2.z + ac2.w;
        float v3 = ac3.x + ac3.y + ac3.z + ac3.w;
        int e = eid[2 * p], re = eid[2 * p + 1];
        float* oe = OutV + (size_t)e * 256;
        oe[(a0 + 0) * 16 + b] = v0;
        oe[(a0 + 1) * 16 + b] = v1;
        oe[(a0 + 2) * 16 + b] = v2;
        oe[(a0 + 3) * 16 + b] = v3;
        sC[w][b][a0 + 0] = v0;
        sC[w][b][a0 + 1] = v1;
        sC[w][b][a0 + 2] = v2;
        sC[w][b][a0 + 3] = v3;
        // wave-internal RAW through LDS: in-order DS + lockstep wave -> safe.
        int rr2 = lane >> 2, cc2 = (lane & 3) * 4;
        float4 t4 = { sC[w][rr2][cc2], sC[w][rr2][cc2 + 1],
                      sC[w][rr2][cc2 + 2], sC[w][rr2][cc2 + 3] };
        *(float4*)(OutV + (size_t)re * 256 + lane * 4) = t4;
    }
}

// ---------------------------------------------------------------------------
// h_fl — unchanged (flags bit-path depends on this exact summation order).
// ---------------------------------------------------------------------------
__global__ __launch_bounds__(256) void hfl_kernel(
    const float* __restrict__ ef, const float* __restrict__ gf,
    const float* __restrict__ Wfl, const float* __restrict__ bfl,
    float* __restrict__ HFL)
{
    __shared__ float Ws[KD][32];    // 24 KB
    __shared__ float xr[64][KD];    // 48 KB
    int tid = threadIdx.x;
    int e0 = blockIdx.x * 64;
    for (int i = tid; i < KD * 32; i += 256) Ws[i >> 5][i & 31] = Wfl[i];
    for (int i4 = tid; i4 < 64 * 48; i4 += 256) {
        int slot = i4 / 48, kq = i4 - slot * 48;
        int e = e0 + slot;
        float4 v;
        if (kq < 32) v = *(const float4*)&ef[(size_t)e * 128 + kq * 4];
        else         v = *(const float4*)&gf[(e / EPG) * 64 + (kq - 32) * 4];
        *(float4*)&xr[slot][kq * 4] = v;
    }
    __syncthreads();
    int j = tid & 31, es = tid >> 5;
    float acc[8];
#pragma unroll
    for (int i = 0; i < 8; ++i) acc[i] = bfl[j];
    for (int k = 0; k < KD; k += 4) {
        float w0 = Ws[k][j], w1 = Ws[k + 1][j], w2 = Ws[k + 2][j], w3 = Ws[k + 3][j];
#pragma unroll
        for (int i = 0; i < 8; ++i) {
            float4 x4 = *(const float4*)&xr[es + 8 * i][k];
            acc[i] += x4.x * w0; acc[i] += x4.y * w1;
            acc[i] += x4.z * w2; acc[i] += x4.w * w3;
        }
    }
#pragma unroll
    for (int i = 0; i < 8; ++i)
        HFL[(size_t)(e0 + es + 8 * i) * 32 + j] = acc[i];
}

// ---------------------------------------------------------------------------
// BP (R20 — unchanged).
// ---------------------------------------------------------------------------
__global__ __launch_bounds__(704) void bp_kernel(
    const float* __restrict__ FV, const float* __restrict__ UV,
    const float* __restrict__ HFL, const float* __restrict__ Wcls,
    const float* __restrict__ bcls, const float* __restrict__ gum,
    const float* __restrict__ IFF, const float* __restrict__ IUU,
    float* __restrict__ out)
{
    int g = blockIdx.x, tid = threadIdx.x;
    __shared__ __align__(16) float fvs[EPG * 256];   // 135.2 KB: fv then E
    __shared__ __align__(16) float2 MU[EPG][16];     // {msg, umsg} 16.9 KB
    __shared__ __align__(16) float2 AU[NPG][16];     // {Asum, Usum}
    __shared__ __align__(16) float2 IU[NPG][16];     // {iff, iuu}
    __shared__ __align__(16) float2 gGU[44][16];     // {G, U} broadcast
    __shared__ float fls[EPG];

    for (int i = tid; i < EPG * 16; i += 704)
        (&MU[0][0])[i] = make_float2(0.f, 0.f);
    if (tid < NPG * 16) {
        float fi = IFF[g * NPG * 16 + tid];
        float ui = IUU[g * NPG * 16 + tid];
        (&IU[0][0])[tid] = make_float2(fi, ui);
        (&AU[0][0])[tid] = make_float2(fi, ui);
    }
    // flags fold (same arithmetic order as original flags_kernel — exact)
    if (tid < EPG) {
        int el = tid, rel = rev_local(el);
        int e = g * EPG + el, re = g * EPG + rel;
        float l0 = bcls[0], l1 = bcls[1];
        const float* ha = HFL + (size_t)e * 32;
        const float* hb = HFL + (size_t)re * 32;
#pragma unroll
        for (int j = 0; j < 32; ++j) {
            float pp = ha[j] * hb[j];
            l0 += pp * Wcls[j * 2 + 0];
            l1 += pp * Wcls[j * 2 + 1];
        }
        int mn = min(e, re);
        l0 += gum[(size_t)mn * 2 + 0];
        l1 += gum[(size_t)mn * 2 + 1];
        fls[el] = (l0 >= l1) ? 1.0f : 0.0f;
    }

    // ---- stage FV into LDS, swizzled: word(e,a,qq) = e*256 + a*16 +
    //      ((qq ^ ((a>>1)&3))<<2).
    const float* fvg = FV + (size_t)g * EPG * 256;
    const float* uvg = UV + (size_t)g * EPG * 256;
    for (int t4 = tid; t4 < EPG * 64; t4 += 704) {
        float4 v = *(const float4*)(fvg + (size_t)t4 * 4);
        int e = t4 >> 6, rem = t4 & 63;
        int aa = rem >> 2, qq = rem & 3;
        int w = e * 256 + aa * 16 + ((qq ^ ((aa >> 1) & 3)) << 2);
        *(float4*)&fvs[w] = v;
    }

    int w44 = tid >> 4, a = tid & 15;
    int bl = (tid & 63) & 48;              // group base lane within wave
    int e0 = w44,      s0 = e0 / 11, r0 = rev_local(e0);
    int e1 = 44 + w44, s1 = e1 / 11, r1 = rev_local(e1);
    int e2 = 88 + w44, s2 = e2 / 11, r2 = rev_local(e2);

    int xr = (a >> 1) & 3;
    int sl0 = ((0 ^ xr) << 2), sl1 = ((1 ^ xr) << 2);
    int sl2 = ((2 ^ xr) << 2), sl3 = ((3 ^ xr) << 2);
    int fb0 = e0 * 256 + a * 16;
    int fb1 = e1 * 256 + a * 16;
    int fb2 = e2 * 256 + a * 16;

    const float* ur0 = uvg + (size_t)e0 * 256 + a * 16;
    const float* ur1 = uvg + (size_t)e1 * 256 + a * 16;
    const float* ur2 = uvg + (size_t)e2 * 256 + a * 16;

    __syncthreads();
    float fl0 = fls[e0], fl1 = fls[e1], fl2 = fls[e2];

    // ---- in-place transform: row (e,a) of fvs: fv -> E = exp(fv - fvmax).
    auto xform = [&](int fbase) -> float {
        float4 a0 = *(const float4*)&fvs[fbase + sl0];
        float4 a1 = *(const float4*)&fvs[fbase + sl1];
        float4 a2 = *(const float4*)&fvs[fbase + sl2];
        float4 a3 = *(const float4*)&fvs[fbase + sl3];
        float mx = fmaxf(fmaxf(fmaxf(a0.x, a0.y), fmaxf(a0.z, a0.w)),
                         fmaxf(fmaxf(a1.x, a1.y), fmaxf(a1.z, a1.w)));
        mx = fmaxf(mx, fmaxf(fmaxf(fmaxf(a2.x, a2.y), fmaxf(a2.z, a2.w)),
                             fmaxf(fmaxf(a3.x, a3.y), fmaxf(a3.z, a3.w))));
        a0.x = __expf(a0.x - mx); a0.y = __expf(a0.y - mx);
        a0.z = __expf(a0.z - mx); a0.w = __expf(a0.w - mx);
        a1.x = __expf(a1.x - mx); a1.y = __expf(a1.y - mx);
        a1.z = __expf(a1.z - mx); a1.w = __expf(a1.w - mx);
        a2.x = __expf(a2.x - mx); a2.y = __expf(a2.y - mx);
        a2.z = __expf(a2.z - mx); a2.w = __expf(a2.w - mx);
        a3.x = __expf(a3.x - mx); a3.y = __expf(a3.y - mx);
        a3.z = __expf(a3.z - mx); a3.w = __expf(a3.w - mx);
        *(float4*)&fvs[fbase + sl0] = a0;
        *(float4*)&fvs[fbase + sl1] = a1;
        *(float4*)&fvs[fbase + sl2] = a2;
        *(float4*)&fvs[fbase + sl3] = a3;
        return mx;
    };
    float fvm0 = xform(fb0);
    float fvm1 = xform(fb1);
    float fvm2 = xform(fb2);

    // edge core (factored): lane a owns b-slot a of the edge's shared agg.
    auto edge_core = [&](int s, int re, int fbase, float fvm,
                         float4 uva, float4 uvb, float4 uvc, float4 uvd,
                         float& lse_o, float& unv_o) {
        float2 au = AU[s][a];
        float2 mu = MU[re][a];
        float aggA  = au.x - mu.x;
        float uaggA = au.y - mu.y;
        float amx = aggA;
        amx = fmaxf(amx, __shfl_xor(amx, 1));
        amx = fmaxf(amx, __shfl_xor(amx, 2));
        amx = fmaxf(amx, __shfl_xor(amx, 4));
        amx = fmaxf(amx, __shfl_xor(amx, 8));
        gGU[w44][a] = make_float2(__expf(aggA - amx), uaggA);
        // same-wave LDS RAW: in-order DS + compiler lgkmcnt make this safe.
        float4 q0 = *(const float4*)&gGU[w44][0];
        float4 q1 = *(const float4*)&gGU[w44][2];
        float4 q2 = *(const float4*)&gGU[w44][4];
        float4 q3 = *(const float4*)&gGU[w44][6];
        float4 q4 = *(const float4*)&gGU[w44][8];
        float4 q5 = *(const float4*)&gGU[w44][10];
        float4 q6 = *(const float4*)&gGU[w44][12];
        float4 q7 = *(const float4*)&gGU[w44][14];
        float4 E0 = *(const float4*)&fvs[fbase + sl0];
        float4 E1 = *(const float4*)&fvs[fbase + sl1];
        float4 E2 = *(const float4*)&fvs[fbase + sl2];
        float4 E3 = *(const float4*)&fvs[fbase + sl3];
        float p0  = E0.x * q0.x, p1  = E0.y * q0.z;
        float p2  = E0.z * q1.x, p3  = E0.w * q1.z;
        float p4  = E1.x * q2.x, p5  = E1.y * q2.z;
        float p6  = E1.z * q3.x, p7  = E1.w * q3.z;
        float p8  = E2.x * q4.x, p9  = E2.y * q4.z;
        float p10 = E2.z * q5.x, p11 = E2.w * q5.z;
        float p12 = E3.x * q6.x, p13 = E3.y * q6.z;
        float p14 = E3.z * q7.x, p15 = E3.w * q7.z;
        float S = (((p0 + p1) + (p2 + p3)) + ((p4 + p5) + (p6 + p7)))
                + (((p8 + p9) + (p10 + p11)) + ((p12 + p13) + (p14 + p15)));
        float n0  = (uva.x + q0.y) * p0,  n1  = (uva.y + q0.w) * p1;
        float n2  = (uva.z + q1.y) * p2,  n3  = (uva.w + q1.w) * p3;
        float n4  = (uvb.x + q2.y) * p4,  n5  = (uvb.y + q2.w) * p5;
        float n6  = (uvb.z + q3.y) * p6,  n7  = (uvb.w + q3.w) * p7;
        float n8  = (uvc.x + q4.y) * p8,  n9  = (uvc.y + q4.w) * p9;
        float n10 = (uvc.z + q5.y) * p10, n11 = (uvc.w + q5.w) * p11;
        float n12 = (uvd.x + q6.y) * p12, n13 = (uvd.y + q6.w) * p13;
        float n14 = (uvd.z + q7.y) * p14, n15 = (uvd.w + q7.w) * p15;
        float num = (((n0 + n1) + (n2 + n3)) + ((n4 + n5) + (n6 + n7)))
                  + (((n8 + n9) + (n10 + n11)) + ((n12 + n13) + (n14 + n15)));
        S = fmaxf(S, 1e-37f);
        lse_o = (fvm + amx) + __logf(S);
        unv_o = num / S;
    };

    for (int it = 0; it < NPG - 1; ++it) {
        // uv reloads issued at iteration top; latency hides under DS chain.
        float4 u0q0 = *(const float4*)(ur0 + 0),  u0q1 = *(const float4*)(ur0 + 4);
        float4 u0q2 = *(const float4*)(ur0 + 8),  u0q3 = *(const float4*)(ur0 + 12);
        float4 u1q0 = *(const float4*)(ur1 + 0),  u1q1 = *(const float4*)(ur1 + 4);
        float4 u1q2 = *(const float4*)(ur1 + 8),  u1q3 = *(const float4*)(ur1 + 12);
        float4 u2q0 = *(const float4*)(ur2 + 0),  u2q1 = *(const float4*)(ur2 + 4);
        float4 u2q2 = *(const float4*)(ur2 + 8),  u2q3 = *(const float4*)(ur2 + 12);

        float lse0, unv0, lse1, unv1, lse2, unv2;
        edge_core(s0, r0, fb0, fvm0, u0q0, u0q1, u0q2, u0q3, lse0, unv0);
        edge_core(s1, r1, fb1, fvm1, u1q0, u1q1, u1q2, u1q3, lse1, unv1);
        edge_core(s2, r2, fb2, fvm2, u2q0, u2q1, u2q2, u2q3, lse2, unv2);
        // finish: normalize by the group's lane-0 lse (1 shfl, per-edge-
        // uniform shift -> cancels exactly next iteration).
        float nm0 = (lse0 - __shfl(lse0, bl)) * fl0;
        float nm1 = (lse1 - __shfl(lse1, bl)) * fl1;
        float nm2 = (lse2 - __shfl(lse2, bl)) * fl2;
        float nu0 = unv0 * fl0, nu1 = unv1 * fl1, nu2 = unv2 * fl2;
        __syncthreads();            // all reads of MU complete
        MU[e0][a] = make_float2(nm0, nu0);
        MU[e1][a] = make_float2(nm1, nu1);
        MU[e2][a] = make_float2(nm2, nu2);
        __syncthreads();            // writes visible to aggregation
        if (tid < NPG * 16) {
            int n = tid >> 4, aa = tid & 15;
            float sm = 0.f, su = 0.f;
#pragma unroll
            for (int s = 0; s < NPG; ++s) {
                if (s == n) continue;
                int le = s * 11 + (n < s ? n : n - 1);
                float2 v = MU[le][aa];
                sm += v.x;
                su += v.y;
            }
            float2 iu = IU[n][aa];
            AU[n][aa] = make_float2(sm + iu.x, su + iu.y);
        }
        __syncthreads();            // AU ready for next iteration
    }

    // ---- final (12th) iteration: only umsg for edges into node 0 ----
    {
        float nu0 = 0.f, nu1 = 0.f, nu2 = 0.f;
        bool own = ((w44 % 11) == 0);
        if (own) {
            float lse, unv;
            if (e0 != 0) {
                float4 q0 = *(const float4*)(ur0 + 0), q1 = *(const float4*)(ur0 + 4);
                float4 q2 = *(const float4*)(ur0 + 8), q3 = *(const float4*)(ur0 + 12);
                edge_core(s0, r0, fb0, fvm0, q0, q1, q2, q3, lse, unv);
                nu0 = unv * fl0;
            }
            {
                float4 q0 = *(const float4*)(ur1 + 0), q1 = *(const float4*)(ur1 + 4);
                float4 q2 = *(const float4*)(ur1 + 8), q3 = *(const float4*)(ur1 + 12);
                edge_core(s1, r1, fb1, fvm1, q0, q1, q2, q3, lse, unv);
                nu1 = unv * fl1;
            }
            {
                float4 q0 = *(const float4*)(ur2 + 0), q1 = *(const float4*)(ur2 + 4);
                float4 q2 = *(const float4*)(ur2 + 8), q3 = *(const float4*)(ur2 + 12);
                edge_core(s2, r2, fb2, fvm2, q0, q1, q2, q3, lse, unv);
                nu2 = unv * fl2;
            }
            (void)lse;
        }
        __syncthreads();            // all reads of MU complete
        if (own) {
            if (e0 != 0) MU[e0][a] = make_float2(0.f, nu0);
            MU[e1][a] = make_float2(0.f, nu1);
            MU[e2][a] = make_float2(0.f, nu2);
        }
        __syncthreads();
        if (tid < 16) {
            float su = 0.f;
#pragma unroll
            for (int s = 1; s < NPG; ++s) su += MU[s * 11][tid].y;
            out[g * 16 + tid] = su + IU[0][tid].y;
        }
    }
}

// ---------------------------------------------------------------------------
extern "C" void kernel_launch(void* const* d_in, const int* in_sizes, int n_in,
                              void* d_out, int out_size, void* d_ws, size_t ws_size,
                              hipStream_t stream) {
    const float* edge_feats  = (const float*)d_in[0];
    const float* node_feats  = (const float*)d_in[1];
    const float* graph_feats = (const float*)d_in[2];
    // d_in[3] edge_feat_reflected: unused (== edge_feats[rev])
    // d_in[4] src, d_in[5] dst, d_in[6] idx_revs: unused (analytic graph structure)
    const float* gumbel      = (const float*)d_in[7];
    const float* W_jf        = (const float*)d_in[8];
    const float* b_jf        = (const float*)d_in[9];
    const float* W_if        = (const float*)d_in[10];
    const float* b_if        = (const float*)d_in[11];
    const float* W_ju        = (const float*)d_in[12];
    const float* b_ju        = (const float*)d_in[13];
    const float* W_iu        = (const float*)d_in[14];
    const float* b_iu        = (const float*)d_in[15];
    const float* W_fl        = (const float*)d_in[16];
    const float* b_fl        = (const float*)d_in[17];
    const float* W_cls       = (const float*)d_in[18];
    const float* b_cls       = (const float*)d_in[19];
    float* out = (float*)d_out;          // reference output dtype is float32
    (void)in_sizes; (void)n_in; (void)out_size; (void)ws_size;

    size_t off = 0;
    char* base = (char*)d_ws;
    auto alloc = [&](size_t bytes) {
        void* p = base + off;
        off += (bytes + 255) & ~(size_t)255;
        return p;
    };
    ushort_t* XeS   = (ushort_t*)alloc((size_t)E_TOT * KD2 * 2);  // 13.0 MB
    ushort_t* WtJFs = (ushort_t*)alloc((size_t)NJ * KD2 * 2);     // 0.39 MB
    ushort_t* WtJUs = (ushort_t*)alloc((size_t)NJ * KD2 * 2);     // 0.39 MB
    float*    CGp   = (float*)   alloc((size_t)2 * 128 * NJ * 4); // 0.52 MB
    float*    HFL   = (float*)   alloc((size_t)E_TOT * 32 * 4);   // 2.16 MB
    float*    IFFp  = (float*)   alloc((size_t)NT * 16 * 4);
    float*    IUUp  = (float*)   alloc((size_t)NT * 16 * 4);
    float*    FVUV  = (float*)   alloc((size_t)E_TOT * 512 * 4);    // 34.6 MB
    float* FVv = FVUV;
    float* UVv = FVUV + (size_t)E_TOT * 256;

    const int prep_blocks = 32 + 1056 + 512 + 192;   // 1792

    prep_kernel<<<prep_blocks, 256, 0, stream>>>(
        W_jf, W_ju, edge_feats, graph_feats, b_jf, b_ju, node_feats,
        W_if, b_if, W_iu, b_iu, WtJFs, WtJUs, XeS, CGp, IFFp, IUUp);
    hfl_kernel<<<E_TOT / 64, 256, 0, stream>>>(edge_feats, graph_feats, W_fl, b_fl, HFL);
    gp_kernel<<<dim3(NCAN / 16, 2), 256, 0, stream>>>(
        XeS, WtJFs, WtJUs, CGp, FVUV);
    bp_kernel<<<BGR, 704, 0, stream>>>(FVv, UVv, HFL, W_cls, b_cls, gumbel,
                                       IFFp, IUUp, out);
}

// Round 11
// 201.530 us; speedup vs baseline: 1.2834x; 1.2834x over previous
//
#include <hip/hip_runtime.h>
#include <hip/hip_bf16.h>

typedef unsigned short ushort_t;
typedef __bf16 bf16x8 __attribute__((ext_vector_type(8)));
typedef float f32x4 __attribute__((ext_vector_type(4)));

// Problem constants
#define E_TOT 16896
#define NT    1536
#define BGR   128
#define NPG   12
#define EPG   132
#define KD    192    // DIM_E + DIM_U
#define KDE   128    // DIM_E only (GEMM K after cg-folding)
#define KD2   384    // split-K over ef: [hi | lo | hi] x [hi | hi | lo]
#define NJ    512    // A*MID
#define NCAN  8448   // canonical edge pairs (s<d): 128 * 66

#if defined(__has_builtin)
#  if __has_builtin(__builtin_amdgcn_global_load_lds)
#    define HAS_GLL 1
#  else
#    define HAS_GLL 0
#  endif
#else
#  define HAS_GLL 0
#endif

#if HAS_GLL
__device__ __forceinline__ void gll16(const ushort_t* g, ushort_t* s) {
    __builtin_amdgcn_global_load_lds(
        (const __attribute__((address_space(1))) unsigned int*)g,
        (__attribute__((address_space(3))) unsigned int*)s, 16, 0, 0);
}
#endif

__device__ __forceinline__ float b2f(ushort_t u) {
    union { float f; unsigned int i; } c; c.i = ((unsigned int)u) << 16; return c.f;
}
__device__ __forceinline__ ushort_t f2b(float f) {
    union { float f; unsigned int i; } c; c.f = f;
    unsigned int i = c.i;
    unsigned int r = (i + 0x7FFFu + ((i >> 16) & 1u)) >> 16;
    return (ushort_t)r;
}
// fully-connected graph: local edge i=(s->d), s=i/11, d with s-skip.
__device__ __forceinline__ int rev_local(int i) {
    int s = i / 11;
    int p = i - 11 * s;
    int d = p + (p >= s ? 1 : 0);
    return d * 11 + (s < d ? s : s - 1);
}

// ---------------------------------------------------------------------------
// prep v2 — coalesced (unchanged).
// ---------------------------------------------------------------------------
__global__ __launch_bounds__(256) void prep_kernel(
    const float* __restrict__ Wjf, const float* __restrict__ Wju,
    const float* __restrict__ ef,  const float* __restrict__ gf,
    const float* __restrict__ bjf, const float* __restrict__ bju,
    const float* __restrict__ nf,
    const float* __restrict__ Wif, const float* __restrict__ bif,
    const float* __restrict__ Wiu, const float* __restrict__ biu,
    ushort_t* __restrict__ WtJFs, ushort_t* __restrict__ WtJUs,
    ushort_t* __restrict__ XeS, float* __restrict__ CG,
    float* __restrict__ IFF, float* __restrict__ IUU)
{
    __shared__ union {
        float tile[64][65];                      // 16.6 KB (transpose)
        struct { float Ws[128 * 32]; float xr[8][128]; } nd;   // 20 KB (node)
    } sm;
    int tid = threadIdx.x;
    unsigned bx = blockIdx.x;

    if (bx < 32u) {
        // ---- W transpose: mat (0=jf,1=ju), 64k x 64n tile ----
        int mat = bx >> 4, t16 = bx & 15;
        int k0 = (t16 >> 3) * 64, n0 = (t16 & 7) * 64;
        const float* W = mat ? Wju : Wjf;
        ushort_t* Wt = mat ? WtJUs : WtJFs;
        int col = tid & 63, rowq = tid >> 6;
#pragma unroll
        for (int i = 0; i < 16; ++i) {
            int kk = i * 4 + rowq;
            sm.tile[kk][col] = W[(size_t)(k0 + kk) * NJ + n0 + col];
        }
        __syncthreads();
        int k = tid & 63;
#pragma unroll
        for (int i = 0; i < 16; ++i) {
            int nn = i * 4 + rowq;
            float wf = sm.tile[k][nn];
            ushort_t hf = f2b(wf);
            ushort_t lo = f2b(wf - b2f(hf));
            ushort_t* dst = Wt + (size_t)(n0 + nn) * KD2 + k0 + k;
            dst[0]   = hf;
            dst[128] = hf;
            dst[256] = lo;
        }
        return;
    }
    if (bx < 1088u) {
        // ---- XeS: thread = (e, k8) handles 8 k's ----
        int t = (int)(bx - 32u) * 256 + tid;
        int e = t >> 4, k8 = t & 15;
        const float* src = ef + (size_t)e * KDE + k8 * 8;
        float4 v0 = *(const float4*)(src);
        float4 v1 = *(const float4*)(src + 4);
        float x[8] = { v0.x, v0.y, v0.z, v0.w, v1.x, v1.y, v1.z, v1.w };
        union { ushort_t u[8]; uint4 v; } hi, lo;
#pragma unroll
        for (int i = 0; i < 8; ++i) {
            ushort_t h = f2b(x[i]);
            hi.u[i] = h;
            lo.u[i] = f2b(x[i] - b2f(h));
        }
        ushort_t* dst = XeS + (size_t)e * KD2 + k8 * 8;
        *(uint4*)(dst)       = hi.v;
        *(uint4*)(dst + 128) = lo.v;
        *(uint4*)(dst + 256) = hi.v;
        return;
    }
    if (bx < 1600u) {
        // ---- cg: cidx = z*65536 + g*512 + n ----
        int cidx = (int)(bx - 1088u) * 256 + tid;
        int z = cidx >> 16;
        int rem = cidx & 65535;
        int g = rem >> 9, n = rem & 511;
        const float* W = z ? Wju : Wjf;
        float acc = (z ? bju : bjf)[n];
        const float* gr = gf + g * 64;
#pragma unroll 8
        for (int k = 0; k < 64; ++k)
            acc += gr[k] * W[(size_t)(KDE + k) * NJ + n];
        CG[cidx] = acc;
        return;
    }
    // ---- node linear: 8 nodes per block ----
    int n0 = (int)(bx - 1600u) * 8;
    for (int i = tid; i < 128 * 32; i += 256) {
        int k = i >> 5, j = i & 31;
        sm.nd.Ws[i] = (j < 16) ? Wif[k * 16 + j] : Wiu[k * 16 + (j - 16)];
    }
    for (int i = tid; i < 8 * 128; i += 256) {
        int slot = i >> 7, k = i & 127;
        int n = n0 + slot;
        sm.nd.xr[slot][k] = (k < 64) ? nf[(size_t)n * 64 + k]
                                     : gf[(n / NPG) * 64 + (k - 64)];
    }
    __syncthreads();
    int slot = tid >> 5, j = tid & 31;
    float acc = (j < 16) ? bif[j] : biu[j - 16];
#pragma unroll 8
    for (int k = 0; k < 128; ++k) acc += sm.nd.xr[slot][k] * sm.nd.Ws[k * 32 + j];
    int n = n0 + slot;
    if (j < 16) IFF[n * 16 + j] = acc;
    else        IUU[n * 16 + (j - 16)] = acc;
}

// ---------------------------------------------------------------------------
// GEMM (K=384): H[z][M,512] = XeS @ Wt_z  (cg add lives in pair — bit-exact).
// R19 grid: linear D = c*136 + by (c = col-block + 4*z); all 8 works sharing
// an XeS row-tile have D%8 == by%8 -> same XCD under round-robin dispatch.
// ---------------------------------------------------------------------------
__global__ __launch_bounds__(256) void gemm_kernel(
    const ushort_t* __restrict__ X,
    const ushort_t* __restrict__ Wt0, const ushort_t* __restrict__ Wt1,
    float* __restrict__ Hbase)
{
    __shared__ ushort_t As[2][128][32];   // 2 x 8 KB
    __shared__ ushort_t Bs[2][128][32];
    unsigned D = blockIdx.x;
    unsigned c = D / 136u, j = D - c * 136u;
    if (j >= 132u) return;
    int z  = (int)(c >> 2);
    int n0 = (int)(c & 3u) * 128;
    int m0 = (int)j * 128;
    const ushort_t* Wt = z ? Wt1 : Wt0;
    float* H = Hbase + (size_t)z * E_TOT * NJ;

    int tid = threadIdx.x, lane = tid & 63, w = tid >> 6;
    int wm = (w >> 1) * 64, wn = (w & 1) * 64;
    int r = lane & 15, q = lane >> 4;
    f32x4 acc[4][4] = {};

    int sr = w * 32 + (lane >> 2);
    int sc = (lane & 3) * 8;
    const ushort_t* xg0 = X  + (size_t)(m0 + sr)      * KD2 + sc;
    const ushort_t* xg1 = X  + (size_t)(m0 + sr + 16) * KD2 + sc;
    const ushort_t* wg0 = Wt + (size_t)(n0 + sr)      * KD2 + sc;
    const ushort_t* wg1 = Wt + (size_t)(n0 + sr + 16) * KD2 + sc;

#if HAS_GLL
    auto stage = [&](int p, int kk) {
        gll16(xg0 + kk, &As[p][w * 32][0]);
        gll16(xg1 + kk, &As[p][w * 32 + 16][0]);
        gll16(wg0 + kk, &Bs[p][w * 32][0]);
        gll16(wg1 + kk, &Bs[p][w * 32 + 16][0]);
    };
#else
    auto stage = [&](int p, int kk) {
        uint4 a0 = *(const uint4*)(xg0 + kk);
        uint4 a1 = *(const uint4*)(xg1 + kk);
        uint4 b0 = *(const uint4*)(wg0 + kk);
        uint4 b1 = *(const uint4*)(wg1 + kk);
        *(uint4*)&As[p][sr][sc]      = a0;
        *(uint4*)&As[p][sr + 16][sc] = a1;
        *(uint4*)&Bs[p][sr][sc]      = b0;
        *(uint4*)&Bs[p][sr + 16][sc] = b1;
    };
#endif

    stage(0, 0);
    int cur = 0;
    for (int kk = 0; kk < KD2; kk += 32) {
        __syncthreads();
        if (kk + 32 < KD2) stage(cur ^ 1, kk + 32);
        bf16x8 af[4], bf[4];
#pragma unroll
        for (int mi = 0; mi < 4; ++mi)
            af[mi] = *(const bf16x8*)&As[cur][wm + mi * 16 + r][q * 8];
#pragma unroll
        for (int ni = 0; ni < 4; ++ni)
            bf[ni] = *(const bf16x8*)&Bs[cur][wn + ni * 16 + r][q * 8];
#pragma unroll
        for (int mi = 0; mi < 4; ++mi)
#pragma unroll
            for (int ni = 0; ni < 4; ++ni)
                acc[mi][ni] = __builtin_amdgcn_mfma_f32_16x16x32_bf16(
                    af[mi], bf[ni], acc[mi][ni], 0, 0, 0);
        cur ^= 1;
    }
#pragma unroll
    for (int ni = 0; ni < 4; ++ni) {
        int col = n0 + wn + ni * 16 + r;
#pragma unroll
        for (int mi = 0; mi < 4; ++mi) {
            int rowb = m0 + wm + mi * 16 + q * 4;
            float* dst = H + (size_t)rowb * NJ + col;
#pragma unroll
            for (int rr = 0; rr < 4; ++rr)
                dst[(size_t)rr * NJ] = acc[mi][ni][rr];
        }
    }
}

// ---------------------------------------------------------------------------
// pair: canonical pairs (s<d); writes both e and rev(e) tiles.
// Adds cg (same fp32 operands/order the old gemm epilogue used — exact).
// ---------------------------------------------------------------------------
__global__ __launch_bounds__(256) void pair_kernel(
    const float* __restrict__ Hbase, const float* __restrict__ CG,
    float* __restrict__ Obase)
{
    __shared__ float sA[4][16][36];
    __shared__ float sB[4][16][36];
    __shared__ float sC[4][16][20];
    const float* H = Hbase + (size_t)blockIdx.y * E_TOT * NJ;
    const float* cgz = CG + (size_t)blockIdx.y * 128 * NJ;
    float* OutV = Obase + (size_t)blockIdx.y * E_TOT * 256;
    int tid = threadIdx.x, w = tid >> 6, lane = tid & 63;
    int c = blockIdx.x * 4 + w;            // canonical pair index
    int gg = c / 66, cl = c - gg * 66;
    int s = 0;
    while (cl >= 11 - s) { cl -= 11 - s; ++s; }
    int d = s + 1 + cl;                    // s < d
    int e  = gg * EPG + s * 11 + (d - 1);  // edge s->d
    int re = gg * EPG + d * 11 + s;        // edge d->s
    const float* hA = H + (size_t)e * NJ;
    const float* hB = H + (size_t)re * NJ;
    int a = lane >> 2, mseg = (lane & 3) * 8;
    float4 va0 = *(const float4*)(hA + a * 32 + mseg);
    float4 va1 = *(const float4*)(hA + a * 32 + mseg + 4);
    float4 vb0 = *(const float4*)(hB + a * 32 + mseg);
    float4 vb1 = *(const float4*)(hB + a * 32 + mseg + 4);
    // cg add (moved from gemm epilogue; same operands, same order -> exact)
    const float* cgr = cgz + (size_t)gg * NJ + a * 32 + mseg;
    float4 cg0 = *(const float4*)(cgr);
    float4 cg1 = *(const float4*)(cgr + 4);
    va0.x += cg0.x; va0.y += cg0.y; va0.z += cg0.z; va0.w += cg0.w;
    va1.x += cg1.x; va1.y += cg1.y; va1.z += cg1.z; va1.w += cg1.w;
    vb0.x += cg0.x; vb0.y += cg0.y; vb0.z += cg0.z; vb0.w += cg0.w;
    vb1.x += cg1.x; vb1.y += cg1.y; vb1.z += cg1.z; vb1.w += cg1.w;
    *(float4*)&sA[w][a][mseg]     = va0;
    *(float4*)&sA[w][a][mseg + 4] = va1;
    *(float4*)&sB[w][a][mseg]     = vb0;
    *(float4*)&sB[w][a][mseg + 4] = vb1;
    __syncthreads();

    int b = lane & 15, a0 = (lane >> 4) * 4;
    float4 ac0 = {0,0,0,0}, ac1 = {0,0,0,0}, ac2 = {0,0,0,0}, ac3 = {0,0,0,0};
#pragma unroll
    for (int m4 = 0; m4 < 8; ++m4) {
        float4 vb = *(const float4*)&sB[w][b][m4 * 4];
        float4 x0 = *(const float4*)&sA[w][a0 + 0][m4 * 4];
        float4 x1 = *(const float4*)&sA[w][a0 + 1][m4 * 4];
        float4 x2 = *(const float4*)&sA[w][a0 + 2][m4 * 4];
        float4 x3 = *(const float4*)&sA[w][a0 + 3][m4 * 4];
        ac0.x += x0.x * vb.x; ac0.y += x0.y * vb.y; ac0.z += x0.z * vb.z; ac0.w += x0.w * vb.w;
        ac1.x += x1.x * vb.x; ac1.y += x1.y * vb.y; ac1.z += x1.z * vb.z; ac1.w += x1.w * vb.w;
        ac2.x += x2.x * vb.x; ac2.y += x2.y * vb.y; ac2.z += x2.z * vb.z; ac2.w += x2.w * vb.w;
        ac3.x += x3.x * vb.x; ac3.y += x3.y * vb.y; ac3.z += x3.z * vb.z; ac3.w += x3.w * vb.w;
    }
    float v0 = ac0.x + ac0.y + ac0.z + ac0.w;
    float v1 = ac1.x + ac1.y + ac1.z + ac1.w;
    float v2 = ac2.x + ac2.y + ac2.z + ac2.w;
    float v3 = ac3.x + ac3.y + ac3.z + ac3.w;
    float* oe = OutV + (size_t)e * 256;
    oe[(a0 + 0) * 16 + b] = v0;
    oe[(a0 + 1) * 16 + b] = v1;
    oe[(a0 + 2) * 16 + b] = v2;
    oe[(a0 + 3) * 16 + b] = v3;
    sC[w][b][a0 + 0] = v0;
    sC[w][b][a0 + 1] = v1;
    sC[w][b][a0 + 2] = v2;
    sC[w][b][a0 + 3] = v3;
    __syncthreads();
    int rr = lane >> 2, cc = (lane & 3) * 4;
    float4 t4 = { sC[w][rr][cc], sC[w][rr][cc + 1], sC[w][rr][cc + 2], sC[w][rr][cc + 3] };
    *(float4*)(OutV + (size_t)re * 256 + lane * 4) = t4;
}

// ---------------------------------------------------------------------------
// h_fl — unchanged (flags bit-path depends on this exact summation order).
// ---------------------------------------------------------------------------
__global__ __launch_bounds__(256) void hfl_kernel(
    const float* __restrict__ ef, const float* __restrict__ gf,
    const float* __restrict__ Wfl, const float* __restrict__ bfl,
    float* __restrict__ HFL)
{
    __shared__ float Ws[KD][32];    // 24 KB
    __shared__ float xr[64][KD];    // 48 KB
    int tid = threadIdx.x;
    int e0 = blockIdx.x * 64;
    for (int i = tid; i < KD * 32; i += 256) Ws[i >> 5][i & 31] = Wfl[i];
    for (int i4 = tid; i4 < 64 * 48; i4 += 256) {
        int slot = i4 / 48, kq = i4 - slot * 48;
        int e = e0 + slot;
        float4 v;
        if (kq < 32) v = *(const float4*)&ef[(size_t)e * 128 + kq * 4];
        else         v = *(const float4*)&gf[(e / EPG) * 64 + (kq - 32) * 4];
        *(float4*)&xr[slot][kq * 4] = v;
    }
    __syncthreads();
    int j = tid & 31, es = tid >> 5;
    float acc[8];
#pragma unroll
    for (int i = 0; i < 8; ++i) acc[i] = bfl[j];
    for (int k = 0; k < KD; k += 4) {
        float w0 = Ws[k][j], w1 = Ws[k + 1][j], w2 = Ws[k + 2][j], w3 = Ws[k + 3][j];
#pragma unroll
        for (int i = 0; i < 8; ++i) {
            float4 x4 = *(const float4*)&xr[es + 8 * i][k];
            acc[i] += x4.x * w0; acc[i] += x4.y * w1;
            acc[i] += x4.z * w2; acc[i] += x4.w * w3;
        }
    }
#pragma unroll
    for (int i = 0; i < 8; ++i)
        HFL[(size_t)(e0 + es + 8 * i) * 32 + j] = acc[i];
}

// ---------------------------------------------------------------------------
// BP (R22): R20 base + per-node normalizer.
// edge_core's per-edge 4-shfl amx is replaced by nrm = AUmax[s], the per-node
// max of AU, computed ONCE per iteration by the 192 aggregation threads.
// Validity: unv = num/S and msg = lse - lse0 are mathematically invariant to
// the normalizer (cancels in ratio/difference); its only job is exp range.
// Range: agg - nrm = (AU - AUmax) - MU <= |MU| ~ 25 -> exp <= ~7e10, safe;
// underflow covered by the 1e-37 guard.  Saves 12 shfl/thread-iter.
// ---------------------------------------------------------------------------
__global__ __launch_bounds__(704) void bp_kernel(
    const float* __restrict__ FV, const float* __restrict__ UV,
    const float* __restrict__ HFL, const float* __restrict__ Wcls,
    const float* __restrict__ bcls, const float* __restrict__ gum,
    const float* __restrict__ IFF, const float* __restrict__ IUU,
    float* __restrict__ out)
{
    int g = blockIdx.x, tid = threadIdx.x;
    __shared__ __align__(16) float fvs[EPG * 256];   // 135.2 KB: fv then E
    __shared__ __align__(16) float2 MU[EPG][16];     // {msg, umsg} 16.9 KB
    __shared__ __align__(16) float2 AU[NPG][16];     // {Asum, Usum}
    __shared__ __align__(16) float2 IU[NPG][16];     // {iff, iuu}
    __shared__ __align__(16) float2 gGU[44][16];     // {G, U} broadcast
    __shared__ float AUmax[NPG];
    __shared__ float fls[EPG];

    for (int i = tid; i < EPG * 16; i += 704)
        (&MU[0][0])[i] = make_float2(0.f, 0.f);
    if (tid < NPG * 16) {
        float fi = IFF[g * NPG * 16 + tid];
        float ui = IUU[g * NPG * 16 + tid];
        (&IU[0][0])[tid] = make_float2(fi, ui);
        (&AU[0][0])[tid] = make_float2(fi, ui);
        float m = fi;
        m = fmaxf(m, __shfl_xor(m, 1));
        m = fmaxf(m, __shfl_xor(m, 2));
        m = fmaxf(m, __shfl_xor(m, 4));
        m = fmaxf(m, __shfl_xor(m, 8));
        if ((tid & 15) == 0) AUmax[tid >> 4] = m;
    }
    // flags fold (same arithmetic order as original flags_kernel — exact)
    if (tid < EPG) {
        int el = tid, rel = rev_local(el);
        int e = g * EPG + el, re = g * EPG + rel;
        float l0 = bcls[0], l1 = bcls[1];
        const float* ha = HFL + (size_t)e * 32;
        const float* hb = HFL + (size_t)re * 32;
#pragma unroll
        for (int j = 0; j < 32; ++j) {
            float pp = ha[j] * hb[j];
            l0 += pp * Wcls[j * 2 + 0];
            l1 += pp * Wcls[j * 2 + 1];
        }
        int mn = min(e, re);
        l0 += gum[(size_t)mn * 2 + 0];
        l1 += gum[(size_t)mn * 2 + 1];
        fls[el] = (l0 >= l1) ? 1.0f : 0.0f;
    }

    // ---- stage FV into LDS, swizzled: word(e,a,qq) = e*256 + a*16 +
    //      ((qq ^ ((a>>1)&3))<<2).
    const float* fvg = FV + (size_t)g * EPG * 256;
    const float* uvg = UV + (size_t)g * EPG * 256;
    for (int t4 = tid; t4 < EPG * 64; t4 += 704) {
        float4 v = *(const float4*)(fvg + (size_t)t4 * 4);
        int e = t4 >> 6, rem = t4 & 63;
        int aa = rem >> 2, qq = rem & 3;
        int w = e * 256 + aa * 16 + ((qq ^ ((aa >> 1) & 3)) << 2);
        *(float4*)&fvs[w] = v;
    }

    int w44 = tid >> 4, a = tid & 15;
    int bl = (tid & 63) & 48;              // group base lane within wave
    int e0 = w44,      s0 = e0 / 11, r0 = rev_local(e0);
    int e1 = 44 + w44, s1 = e1 / 11, r1 = rev_local(e1);
    int e2 = 88 + w44, s2 = e2 / 11, r2 = rev_local(e2);

    int xr = (a >> 1) & 3;
    int sl0 = ((0 ^ xr) << 2), sl1 = ((1 ^ xr) << 2);
    int sl2 = ((2 ^ xr) << 2), sl3 = ((3 ^ xr) << 2);
    int fb0 = e0 * 256 + a * 16;
    int fb1 = e1 * 256 + a * 16;
    int fb2 = e2 * 256 + a * 16;

    const float* ur0 = uvg + (size_t)e0 * 256 + a * 16;
    const float* ur1 = uvg + (size_t)e1 * 256 + a * 16;
    const float* ur2 = uvg + (size_t)e2 * 256 + a * 16;

    __syncthreads();
    float fl0 = fls[e0], fl1 = fls[e1], fl2 = fls[e2];

    // ---- in-place transform: row (e,a) of fvs: fv -> E = exp(fv - fvmax).
    auto xform = [&](int fbase) -> float {
        float4 a0 = *(const float4*)&fvs[fbase + sl0];
        float4 a1 = *(const float4*)&fvs[fbase + sl1];
        float4 a2 = *(const float4*)&fvs[fbase + sl2];
        float4 a3 = *(const float4*)&fvs[fbase + sl3];
        float mx = fmaxf(fmaxf(fmaxf(a0.x, a0.y), fmaxf(a0.z, a0.w)),
                         fmaxf(fmaxf(a1.x, a1.y), fmaxf(a1.z, a1.w)));
        mx = fmaxf(mx, fmaxf(fmaxf(fmaxf(a2.x, a2.y), fmaxf(a2.z, a2.w)),
                             fmaxf(fmaxf(a3.x, a3.y), fmaxf(a3.z, a3.w))));
        a0.x = __expf(a0.x - mx); a0.y = __expf(a0.y - mx);
        a0.z = __expf(a0.z - mx); a0.w = __expf(a0.w - mx);
        a1.x = __expf(a1.x - mx); a1.y = __expf(a1.y - mx);
        a1.z = __expf(a1.z - mx); a1.w = __expf(a1.w - mx);
        a2.x = __expf(a2.x - mx); a2.y = __expf(a2.y - mx);
        a2.z = __expf(a2.z - mx); a2.w = __expf(a2.w - mx);
        a3.x = __expf(a3.x - mx); a3.y = __expf(a3.y - mx);
        a3.z = __expf(a3.z - mx); a3.w = __expf(a3.w - mx);
        *(float4*)&fvs[fbase + sl0] = a0;
        *(float4*)&fvs[fbase + sl1] = a1;
        *(float4*)&fvs[fbase + sl2] = a2;
        *(float4*)&fvs[fbase + sl3] = a3;
        return mx;
    };
    float fvm0 = xform(fb0);
    float fvm1 = xform(fb1);
    float fvm2 = xform(fb2);

    // edge core (factored): lane a owns b-slot a of the edge's shared agg.
    // Normalizer is the per-node AUmax (precomputed) — no per-edge shfl.
    auto edge_core = [&](int s, int re, int fbase, float fvm,
                         float4 uva, float4 uvb, float4 uvc, float4 uvd,
                         float& lse_o, float& unv_o) {
        float2 au = AU[s][a];
        float2 mu = MU[re][a];
        float aggA  = au.x - mu.x;
        float uaggA = au.y - mu.y;
        float nrm = AUmax[s];
        gGU[w44][a] = make_float2(__expf(aggA - nrm), uaggA);
        // same-wave LDS RAW: in-order DS + compiler lgkmcnt make this safe.
        float4 q0 = *(const float4*)&gGU[w44][0];
        float4 q1 = *(const float4*)&gGU[w44][2];
        float4 q2 = *(const float4*)&gGU[w44][4];
        float4 q3 = *(const float4*)&gGU[w44][6];
        float4 q4 = *(const float4*)&gGU[w44][8];
        float4 q5 = *(const float4*)&gGU[w44][10];
        float4 q6 = *(const float4*)&gGU[w44][12];
        float4 q7 = *(const float4*)&gGU[w44][14];
        float4 E0 = *(const float4*)&fvs[fbase + sl0];
        float4 E1 = *(const float4*)&fvs[fbase + sl1];
        float4 E2 = *(const float4*)&fvs[fbase + sl2];
        float4 E3 = *(const float4*)&fvs[fbase + sl3];
        float p0  = E0.x * q0.x, p1  = E0.y * q0.z;
        float p2  = E0.z * q1.x, p3  = E0.w * q1.z;
        float p4  = E1.x * q2.x, p5  = E1.y * q2.z;
        float p6  = E1.z * q3.x, p7  = E1.w * q3.z;
        float p8  = E2.x * q4.x, p9  = E2.y * q4.z;
        float p10 = E2.z * q5.x, p11 = E2.w * q5.z;
        float p12 = E3.x * q6.x, p13 = E3.y * q6.z;
        float p14 = E3.z * q7.x, p15 = E3.w * q7.z;
        float S = (((p0 + p1) + (p2 + p3)) + ((p4 + p5) + (p6 + p7)))
                + (((p8 + p9) + (p10 + p11)) + ((p12 + p13) + (p14 + p15)));
        float n0  = (uva.x + q0.y) * p0,  n1  = (uva.y + q0.w) * p1;
        float n2  = (uva.z + q1.y) * p2,  n3  = (uva.w + q1.w) * p3;
        float n4  = (uvb.x + q2.y) * p4,  n5  = (uvb.y + q2.w) * p5;
        float n6  = (uvb.z + q3.y) * p6,  n7  = (uvb.w + q3.w) * p7;
        float n8  = (uvc.x + q4.y) * p8,  n9  = (uvc.y + q4.w) * p9;
        float n10 = (uvc.z + q5.y) * p10, n11 = (uvc.w + q5.w) * p11;
        float n12 = (uvd.x + q6.y) * p12, n13 = (uvd.y + q6.w) * p13;
        float n14 = (uvd.z + q7.y) * p14, n15 = (uvd.w + q7.w) * p15;
        float num = (((n0 + n1) + (n2 + n3)) + ((n4 + n5) + (n6 + n7)))
                  + (((n8 + n9) + (n10 + n11)) + ((n12 + n13) + (n14 + n15)));
        S = fmaxf(S, 1e-37f);
        lse_o = (fvm + nrm) + __logf(S);
        unv_o = num / S;
    };

    for (int it = 0; it < NPG - 1; ++it) {
        // uv reloads issued at iteration top; latency hides under DS chain.
        float4 u0q0 = *(const float4*)(ur0 + 0),  u0q1 = *(const float4*)(ur0 + 4);
        float4 u0q2 = *(const float4*)(ur0 + 8),  u0q3 = *(const float4*)(ur0 + 12);
        float4 u1q0 = *(const float4*)(ur1 + 0),  u1q1 = *(const float4*)(ur1 + 4);
        float4 u1q2 = *(const float4*)(ur1 + 8),  u1q3 = *(const float4*)(ur1 + 12);
        float4 u2q0 = *(const float4*)(ur2 + 0),  u2q1 = *(const float4*)(ur2 + 4);
        float4 u2q2 = *(const float4*)(ur2 + 8),  u2q3 = *(const float4*)(ur2 + 12);

        float lse0, unv0, lse1, unv1, lse2, unv2;
        edge_core(s0, r0, fb0, fvm0, u0q0, u0q1, u0q2, u0q3, lse0, unv0);
        edge_core(s1, r1, fb1, fvm1, u1q0, u1q1, u1q2, u1q3, lse1, unv1);
        edge_core(s2, r2, fb2, fvm2, u2q0, u2q1, u2q2, u2q3, lse2, unv2);
        // finish: normalize by the group's lane-0 lse (1 shfl, per-edge-
        // uniform shift -> cancels exactly next iteration).
        float nm0 = (lse0 - __shfl(lse0, bl)) * fl0;
        float nm1 = (lse1 - __shfl(lse1, bl)) * fl1;
        float nm2 = (lse2 - __shfl(lse2, bl)) * fl2;
        float nu0 = unv0 * fl0, nu1 = unv1 * fl1, nu2 = unv2 * fl2;
        __syncthreads();            // all reads of MU complete
        MU[e0][a] = make_float2(nm0, nu0);
        MU[e1][a] = make_float2(nm1, nu1);
        MU[e2][a] = make_float2(nm2, nu2);
        __syncthreads();            // writes visible to aggregation
        if (tid < NPG * 16) {
            int n = tid >> 4, aa = tid & 15;
            float sm = 0.f, su = 0.f;
#pragma unroll
            for (int s = 0; s < NPG; ++s) {
                if (s == n) continue;
                int le = s * 11 + (n < s ? n : n - 1);
                float2 v = MU[le][aa];
                sm += v.x;
                su += v.y;
            }
            float2 iu = IU[n][aa];
            float as = sm + iu.x;
            AU[n][aa] = make_float2(as, su + iu.y);
            float m = as;
            m = fmaxf(m, __shfl_xor(m, 1));
            m = fmaxf(m, __shfl_xor(m, 2));
            m = fmaxf(m, __shfl_xor(m, 4));
            m = fmaxf(m, __shfl_xor(m, 8));
            if (aa == 0) AUmax[n] = m;
        }
        __syncthreads();            // AU + AUmax ready for next iteration
    }

    // ---- final (12th) iteration: only umsg for edges into node 0 ----
    {
        float nu0 = 0.f, nu1 = 0.f, nu2 = 0.f;
        bool own = ((w44 % 11) == 0);
        if (own) {
            float lse, unv;
            if (e0 != 0) {
                float4 q0 = *(const float4*)(ur0 + 0), q1 = *(const float4*)(ur0 + 4);
                float4 q2 = *(const float4*)(ur0 + 8), q3 = *(const float4*)(ur0 + 12);
                edge_core(s0, r0, fb0, fvm0, q0, q1, q2, q3, lse, unv);
                nu0 = unv * fl0;
            }
            {
                float4 q0 = *(const float4*)(ur1 + 0), q1 = *(const float4*)(ur1 + 4);
                float4 q2 = *(const float4*)(ur1 + 8), q3 = *(const float4*)(ur1 + 12);
                edge_core(s1, r1, fb1, fvm1, q0, q1, q2, q3, lse, unv);
                nu1 = unv * fl1;
            }
            {
                float4 q0 = *(const float4*)(ur2 + 0), q1 = *(const float4*)(ur2 + 4);
                float4 q2 = *(const float4*)(ur2 + 8), q3 = *(const float4*)(ur2 + 12);
                edge_core(s2, r2, fb2, fvm2, q0, q1, q2, q3, lse, unv);
                nu2 = unv * fl2;
            }
            (void)lse;
        }
        __syncthreads();            // all reads of MU complete
        if (own) {
            if (e0 != 0) MU[e0][a] = make_float2(0.f, nu0);
            MU[e1][a] = make_float2(0.f, nu1);
            MU[e2][a] = make_float2(0.f, nu2);
        }
        __syncthreads();
        if (tid < 16) {
            float su = 0.f;
#pragma unroll
            for (int s = 1; s < NPG; ++s) su += MU[s * 11][tid].y;
            out[g * 16 + tid] = su + IU[0][tid].y;
        }
    }
}

// ---------------------------------------------------------------------------
extern "C" void kernel_launch(void* const* d_in, const int* in_sizes, int n_in,
                              void* d_out, int out_size, void* d_ws, size_t ws_size,
                              hipStream_t stream) {
    const float* edge_feats  = (const float*)d_in[0];
    const float* node_feats  = (const float*)d_in[1];
    const float* graph_feats = (const float*)d_in[2];
    // d_in[3] edge_feat_reflected: unused (== edge_feats[rev])
    // d_in[4] src, d_in[5] dst, d_in[6] idx_revs: unused (analytic graph structure)
    const float* gumbel      = (const float*)d_in[7];
    const float* W_jf        = (const float*)d_in[8];
    const float* b_jf        = (const float*)d_in[9];
    const float* W_if        = (const float*)d_in[10];
    const float* b_if        = (const float*)d_in[11];
    const float* W_ju        = (const float*)d_in[12];
    const float* b_ju        = (const float*)d_in[13];
    const float* W_iu        = (const float*)d_in[14];
    const float* b_iu        = (const float*)d_in[15];
    const float* W_fl        = (const float*)d_in[16];
    const float* b_fl        = (const float*)d_in[17];
    const float* W_cls       = (const float*)d_in[18];
    const float* b_cls       = (const float*)d_in[19];
    float* out = (float*)d_out;          // reference output dtype is float32
    (void)in_sizes; (void)n_in; (void)out_size; (void)ws_size;

    size_t off = 0;
    char* base = (char*)d_ws;
    auto alloc = [&](size_t bytes) {
        void* p = base + off;
        off += (bytes + 255) & ~(size_t)255;
        return p;
    };
    ushort_t* XeS   = (ushort_t*)alloc((size_t)E_TOT * KD2 * 2);  // 13.0 MB
    ushort_t* WtJFs = (ushort_t*)alloc((size_t)NJ * KD2 * 2);     // 0.39 MB
    ushort_t* WtJUs = (ushort_t*)alloc((size_t)NJ * KD2 * 2);     // 0.39 MB
    float*    CGp   = (float*)   alloc((size_t)2 * 128 * NJ * 4); // 0.52 MB
    float*    HFL   = (float*)   alloc((size_t)E_TOT * 32 * 4);   // 2.16 MB
    float*    IFFp  = (float*)   alloc((size_t)NT * 16 * 4);
    float*    IUUp  = (float*)   alloc((size_t)NT * 16 * 4);
    float*    H2    = (float*)   alloc((size_t)E_TOT * NJ * 2 * 4); // 69.2 MB
    float*    FVUV  = (float*)   alloc((size_t)E_TOT * 512 * 4);    // 34.6 MB
    float* FVv = FVUV;
    float* UVv = FVUV + (size_t)E_TOT * 256;

    const int prep_blocks = 32 + 1056 + 512 + 192;   // 1792

    prep_kernel<<<prep_blocks, 256, 0, stream>>>(
        W_jf, W_ju, edge_feats, graph_feats, b_jf, b_ju, node_feats,
        W_if, b_if, W_iu, b_iu, WtJFs, WtJUs, XeS, CGp, IFFp, IUUp);
    hfl_kernel<<<E_TOT / 64, 256, 0, stream>>>(edge_feats, graph_feats, W_fl, b_fl, HFL);
    gemm_kernel<<<1088, 256, 0, stream>>>(XeS, WtJFs, WtJUs, H2);
    pair_kernel<<<dim3(NCAN / 4, 2), 256, 0, stream>>>(H2, CGp, FVUV);
    bp_kernel<<<BGR, 704, 0, stream>>>(FVv, UVv, HFL, W_cls, b_cls, gumbel,
                                       IFFp, IUUp, out);
}

// Round 12
// 199.001 us; speedup vs baseline: 1.2997x; 1.0127x over previous
//
#include <hip/hip_runtime.h>
#include <hip/hip_bf16.h>

typedef unsigned short ushort_t;
typedef __bf16 bf16x8 __attribute__((ext_vector_type(8)));
typedef float f32x4 __attribute__((ext_vector_type(4)));

// Problem constants
#define E_TOT 16896
#define NT    1536
#define BGR   128
#define NPG   12
#define EPG   132
#define KD    192    // DIM_E + DIM_U
#define KDE   128    // DIM_E only (GEMM K after cg-folding)
#define KD2   384    // split-K over ef: [hi | lo | hi] x [hi | hi | lo]
#define NJ    512    // A*MID
#define NCAN  8448   // canonical edge pairs (s<d): 128 * 66

#if defined(__has_builtin)
#  if __has_builtin(__builtin_amdgcn_global_load_lds)
#    define HAS_GLL 1
#  else
#    define HAS_GLL 0
#  endif
#else
#  define HAS_GLL 0
#endif

#if HAS_GLL
__device__ __forceinline__ void gll16(const ushort_t* g, ushort_t* s) {
    __builtin_amdgcn_global_load_lds(
        (const __attribute__((address_space(1))) unsigned int*)g,
        (__attribute__((address_space(3))) unsigned int*)s, 16, 0, 0);
}
#endif

__device__ __forceinline__ float b2f(ushort_t u) {
    union { float f; unsigned int i; } c; c.i = ((unsigned int)u) << 16; return c.f;
}
__device__ __forceinline__ ushort_t f2b(float f) {
    union { float f; unsigned int i; } c; c.f = f;
    unsigned int i = c.i;
    unsigned int r = (i + 0x7FFFu + ((i >> 16) & 1u)) >> 16;
    return (ushort_t)r;
}
// fully-connected graph: local edge i=(s->d), s=i/11, d with s-skip.
__device__ __forceinline__ int rev_local(int i) {
    int s = i / 11;
    int p = i - 11 * s;
    int d = p + (p >= s ? 1 : 0);
    return d * 11 + (s < d ? s : s - 1);
}

// ---------------------------------------------------------------------------
// prep v3 — R23: hfl merged in as a 5th block-range (bodies verbatim; one
// fewer dispatch).  Ranges:
//  A [0,32): W-transpose.  B [32,1088): XeS build.  C [1088,1600): cg.
//  D [1600,1792): node linear.  E [1792,2056): h_fl (old hfl_kernel).
// LDS union grows to 72 KB (hfl's Ws+xr) -> streaming ranges cap at
// 2 blocks/CU = 8 waves, still ample for 13 MB streaming.
// ---------------------------------------------------------------------------
__global__ __launch_bounds__(256) void prep_kernel(
    const float* __restrict__ Wjf, const float* __restrict__ Wju,
    const float* __restrict__ ef,  const float* __restrict__ gf,
    const float* __restrict__ bjf, const float* __restrict__ bju,
    const float* __restrict__ nf,
    const float* __restrict__ Wif, const float* __restrict__ bif,
    const float* __restrict__ Wiu, const float* __restrict__ biu,
    const float* __restrict__ Wfl, const float* __restrict__ bfl,
    ushort_t* __restrict__ WtJFs, ushort_t* __restrict__ WtJUs,
    ushort_t* __restrict__ XeS, float* __restrict__ CG,
    float* __restrict__ IFF, float* __restrict__ IUU,
    float* __restrict__ HFL)
{
    __shared__ union {
        float tile[64][65];                      // 16.6 KB (transpose)
        struct { float Ws[128 * 32]; float xr[8][128]; } nd;   // 20 KB (node)
        struct { float Ws[KD * 32]; float xr[64 * KD]; } hf;   // 72 KB (hfl)
    } sm;
    int tid = threadIdx.x;
    unsigned bx = blockIdx.x;

    if (bx < 32u) {
        // ---- W transpose: mat (0=jf,1=ju), 64k x 64n tile ----
        int mat = bx >> 4, t16 = bx & 15;
        int k0 = (t16 >> 3) * 64, n0 = (t16 & 7) * 64;
        const float* W = mat ? Wju : Wjf;
        ushort_t* Wt = mat ? WtJUs : WtJFs;
        int col = tid & 63, rowq = tid >> 6;
#pragma unroll
        for (int i = 0; i < 16; ++i) {
            int kk = i * 4 + rowq;
            sm.tile[kk][col] = W[(size_t)(k0 + kk) * NJ + n0 + col];
        }
        __syncthreads();
        int k = tid & 63;
#pragma unroll
        for (int i = 0; i < 16; ++i) {
            int nn = i * 4 + rowq;
            float wf = sm.tile[k][nn];
            ushort_t hf = f2b(wf);
            ushort_t lo = f2b(wf - b2f(hf));
            ushort_t* dst = Wt + (size_t)(n0 + nn) * KD2 + k0 + k;
            dst[0]   = hf;
            dst[128] = hf;
            dst[256] = lo;
        }
        return;
    }
    if (bx < 1088u) {
        // ---- XeS: thread = (e, k8) handles 8 k's ----
        int t = (int)(bx - 32u) * 256 + tid;
        int e = t >> 4, k8 = t & 15;
        const float* src = ef + (size_t)e * KDE + k8 * 8;
        float4 v0 = *(const float4*)(src);
        float4 v1 = *(const float4*)(src + 4);
        float x[8] = { v0.x, v0.y, v0.z, v0.w, v1.x, v1.y, v1.z, v1.w };
        union { ushort_t u[8]; uint4 v; } hi, lo;
#pragma unroll
        for (int i = 0; i < 8; ++i) {
            ushort_t h = f2b(x[i]);
            hi.u[i] = h;
            lo.u[i] = f2b(x[i] - b2f(h));
        }
        ushort_t* dst = XeS + (size_t)e * KD2 + k8 * 8;
        *(uint4*)(dst)       = hi.v;
        *(uint4*)(dst + 128) = lo.v;
        *(uint4*)(dst + 256) = hi.v;
        return;
    }
    if (bx < 1600u) {
        // ---- cg: cidx = z*65536 + g*512 + n ----
        int cidx = (int)(bx - 1088u) * 256 + tid;
        int z = cidx >> 16;
        int rem = cidx & 65535;
        int g = rem >> 9, n = rem & 511;
        const float* W = z ? Wju : Wjf;
        float acc = (z ? bju : bjf)[n];
        const float* gr = gf + g * 64;
#pragma unroll 8
        for (int k = 0; k < 64; ++k)
            acc += gr[k] * W[(size_t)(KDE + k) * NJ + n];
        CG[cidx] = acc;
        return;
    }
    if (bx < 1792u) {
        // ---- node linear: 8 nodes per block ----
        int n0 = (int)(bx - 1600u) * 8;
        for (int i = tid; i < 128 * 32; i += 256) {
            int k = i >> 5, j = i & 31;
            sm.nd.Ws[i] = (j < 16) ? Wif[k * 16 + j] : Wiu[k * 16 + (j - 16)];
        }
        for (int i = tid; i < 8 * 128; i += 256) {
            int slot = i >> 7, k = i & 127;
            int n = n0 + slot;
            sm.nd.xr[slot][k] = (k < 64) ? nf[(size_t)n * 64 + k]
                                         : gf[(n / NPG) * 64 + (k - 64)];
        }
        __syncthreads();
        int slot = tid >> 5, j = tid & 31;
        float acc = (j < 16) ? bif[j] : biu[j - 16];
#pragma unroll 8
        for (int k = 0; k < 128; ++k)
            acc += sm.nd.xr[slot][k] * sm.nd.Ws[k * 32 + j];
        int n = n0 + slot;
        if (j < 16) IFF[n * 16 + j] = acc;
        else        IUU[n * 16 + (j - 16)] = acc;
        return;
    }
    // ---- h_fl range (old hfl_kernel, body verbatim — the flags bit-path
    //      depends on this exact summation order) ----
    {
        float (*Ws)[32] = (float(*)[32])sm.hf.Ws;
        float (*xr)[KD] = (float(*)[KD])sm.hf.xr;
        int e0 = (int)(bx - 1792u) * 64;
        for (int i = tid; i < KD * 32; i += 256) Ws[i >> 5][i & 31] = Wfl[i];
        for (int i4 = tid; i4 < 64 * 48; i4 += 256) {
            int slot = i4 / 48, kq = i4 - slot * 48;
            int e = e0 + slot;
            float4 v;
            if (kq < 32) v = *(const float4*)&ef[(size_t)e * 128 + kq * 4];
            else         v = *(const float4*)&gf[(e / EPG) * 64 + (kq - 32) * 4];
            *(float4*)&xr[slot][kq * 4] = v;
        }
        __syncthreads();
        int j = tid & 31, es = tid >> 5;
        float acc[8];
#pragma unroll
        for (int i = 0; i < 8; ++i) acc[i] = bfl[j];
        for (int k = 0; k < KD; k += 4) {
            float w0 = Ws[k][j], w1 = Ws[k + 1][j], w2 = Ws[k + 2][j], w3 = Ws[k + 3][j];
#pragma unroll
            for (int i = 0; i < 8; ++i) {
                float4 x4 = *(const float4*)&xr[es + 8 * i][k];
                acc[i] += x4.x * w0; acc[i] += x4.y * w1;
                acc[i] += x4.z * w2; acc[i] += x4.w * w3;
            }
        }
#pragma unroll
        for (int i = 0; i < 8; ++i)
            HFL[(size_t)(e0 + es + 8 * i) * 32 + j] = acc[i];
    }
}

// ---------------------------------------------------------------------------
// GEMM (K=384): H[z][M,512] = XeS @ Wt_z  (cg add lives in pair — bit-exact).
// R19 grid: linear D = c*136 + by (c = col-block + 4*z); all 8 works sharing
// an XeS row-tile have D%8 == by%8 -> same XCD under round-robin dispatch.
// ---------------------------------------------------------------------------
__global__ __launch_bounds__(256) void gemm_kernel(
    const ushort_t* __restrict__ X,
    const ushort_t* __restrict__ Wt0, const ushort_t* __restrict__ Wt1,
    float* __restrict__ Hbase)
{
    __shared__ ushort_t As[2][128][32];   // 2 x 8 KB
    __shared__ ushort_t Bs[2][128][32];
    unsigned D = blockIdx.x;
    unsigned c = D / 136u, j = D - c * 136u;
    if (j >= 132u) return;
    int z  = (int)(c >> 2);
    int n0 = (int)(c & 3u) * 128;
    int m0 = (int)j * 128;
    const ushort_t* Wt = z ? Wt1 : Wt0;
    float* H = Hbase + (size_t)z * E_TOT * NJ;

    int tid = threadIdx.x, lane = tid & 63, w = tid >> 6;
    int wm = (w >> 1) * 64, wn = (w & 1) * 64;
    int r = lane & 15, q = lane >> 4;
    f32x4 acc[4][4] = {};

    int sr = w * 32 + (lane >> 2);
    int sc = (lane & 3) * 8;
    const ushort_t* xg0 = X  + (size_t)(m0 + sr)      * KD2 + sc;
    const ushort_t* xg1 = X  + (size_t)(m0 + sr + 16) * KD2 + sc;
    const ushort_t* wg0 = Wt + (size_t)(n0 + sr)      * KD2 + sc;
    const ushort_t* wg1 = Wt + (size_t)(n0 + sr + 16) * KD2 + sc;

#if HAS_GLL
    auto stage = [&](int p, int kk) {
        gll16(xg0 + kk, &As[p][w * 32][0]);
        gll16(xg1 + kk, &As[p][w * 32 + 16][0]);
        gll16(wg0 + kk, &Bs[p][w * 32][0]);
        gll16(wg1 + kk, &Bs[p][w * 32 + 16][0]);
    };
#else
    auto stage = [&](int p, int kk) {
        uint4 a0 = *(const uint4*)(xg0 + kk);
        uint4 a1 = *(const uint4*)(xg1 + kk);
        uint4 b0 = *(const uint4*)(wg0 + kk);
        uint4 b1 = *(const uint4*)(wg1 + kk);
        *(uint4*)&As[p][sr][sc]      = a0;
        *(uint4*)&As[p][sr + 16][sc] = a1;
        *(uint4*)&Bs[p][sr][sc]      = b0;
        *(uint4*)&Bs[p][sr + 16][sc] = b1;
    };
#endif

    stage(0, 0);
    int cur = 0;
    for (int kk = 0; kk < KD2; kk += 32) {
        __syncthreads();
        if (kk + 32 < KD2) stage(cur ^ 1, kk + 32);
        bf16x8 af[4], bf[4];
#pragma unroll
        for (int mi = 0; mi < 4; ++mi)
            af[mi] = *(const bf16x8*)&As[cur][wm + mi * 16 + r][q * 8];
#pragma unroll
        for (int ni = 0; ni < 4; ++ni)
            bf[ni] = *(const bf16x8*)&Bs[cur][wn + ni * 16 + r][q * 8];
#pragma unroll
        for (int mi = 0; mi < 4; ++mi)
#pragma unroll
            for (int ni = 0; ni < 4; ++ni)
                acc[mi][ni] = __builtin_amdgcn_mfma_f32_16x16x32_bf16(
                    af[mi], bf[ni], acc[mi][ni], 0, 0, 0);
        cur ^= 1;
    }
#pragma unroll
    for (int ni = 0; ni < 4; ++ni) {
        int col = n0 + wn + ni * 16 + r;
#pragma unroll
        for (int mi = 0; mi < 4; ++mi) {
            int rowb = m0 + wm + mi * 16 + q * 4;
            float* dst = H + (size_t)rowb * NJ + col;
#pragma unroll
            for (int rr = 0; rr < 4; ++rr)
                dst[(size_t)rr * NJ] = acc[mi][ni][rr];
        }
    }
}

// ---------------------------------------------------------------------------
// pair: canonical pairs (s<d); writes both e and rev(e) tiles.
// Adds cg (same fp32 operands/order the old gemm epilogue used — exact).
// ---------------------------------------------------------------------------
__global__ __launch_bounds__(256) void pair_kernel(
    const float* __restrict__ Hbase, const float* __restrict__ CG,
    float* __restrict__ Obase)
{
    __shared__ float sA[4][16][36];
    __shared__ float sB[4][16][36];
    __shared__ float sC[4][16][20];
    const float* H = Hbase + (size_t)blockIdx.y * E_TOT * NJ;
    const float* cgz = CG + (size_t)blockIdx.y * 128 * NJ;
    float* OutV = Obase + (size_t)blockIdx.y * E_TOT * 256;
    int tid = threadIdx.x, w = tid >> 6, lane = tid & 63;
    int c = blockIdx.x * 4 + w;            // canonical pair index
    int gg = c / 66, cl = c - gg * 66;
    int s = 0;
    while (cl >= 11 - s) { cl -= 11 - s; ++s; }
    int d = s + 1 + cl;                    // s < d
    int e  = gg * EPG + s * 11 + (d - 1);  // edge s->d
    int re = gg * EPG + d * 11 + s;        // edge d->s
    const float* hA = H + (size_t)e * NJ;
    const float* hB = H + (size_t)re * NJ;
    int a = lane >> 2, mseg = (lane & 3) * 8;
    float4 va0 = *(const float4*)(hA + a * 32 + mseg);
    float4 va1 = *(const float4*)(hA + a * 32 + mseg + 4);
    float4 vb0 = *(const float4*)(hB + a * 32 + mseg);
    float4 vb1 = *(const float4*)(hB + a * 32 + mseg + 4);
    // cg add (moved from gemm epilogue; same operands, same order -> exact)
    const float* cgr = cgz + (size_t)gg * NJ + a * 32 + mseg;
    float4 cg0 = *(const float4*)(cgr);
    float4 cg1 = *(const float4*)(cgr + 4);
    va0.x += cg0.x; va0.y += cg0.y; va0.z += cg0.z; va0.w += cg0.w;
    va1.x += cg1.x; va1.y += cg1.y; va1.z += cg1.z; va1.w += cg1.w;
    vb0.x += cg0.x; vb0.y += cg0.y; vb0.z += cg0.z; vb0.w += cg0.w;
    vb1.x += cg1.x; vb1.y += cg1.y; vb1.z += cg1.z; vb1.w += cg1.w;
    *(float4*)&sA[w][a][mseg]     = va0;
    *(float4*)&sA[w][a][mseg + 4] = va1;
    *(float4*)&sB[w][a][mseg]     = vb0;
    *(float4*)&sB[w][a][mseg + 4] = vb1;
    __syncthreads();

    int b = lane & 15, a0 = (lane >> 4) * 4;
    float4 ac0 = {0,0,0,0}, ac1 = {0,0,0,0}, ac2 = {0,0,0,0}, ac3 = {0,0,0,0};
#pragma unroll
    for (int m4 = 0; m4 < 8; ++m4) {
        float4 vb = *(const float4*)&sB[w][b][m4 * 4];
        float4 x0 = *(const float4*)&sA[w][a0 + 0][m4 * 4];
        float4 x1 = *(const float4*)&sA[w][a0 + 1][m4 * 4];
        float4 x2 = *(const float4*)&sA[w][a0 + 2][m4 * 4];
        float4 x3 = *(const float4*)&sA[w][a0 + 3][m4 * 4];
        ac0.x += x0.x * vb.x; ac0.y += x0.y * vb.y; ac0.z += x0.z * vb.z; ac0.w += x0.w * vb.w;
        ac1.x += x1.x * vb.x; ac1.y += x1.y * vb.y; ac1.z += x1.z * vb.z; ac1.w += x1.w * vb.w;
        ac2.x += x2.x * vb.x; ac2.y += x2.y * vb.y; ac2.z += x2.z * vb.z; ac2.w += x2.w * vb.w;
        ac3.x += x3.x * vb.x; ac3.y += x3.y * vb.y; ac3.z += x3.z * vb.z; ac3.w += x3.w * vb.w;
    }
    float v0 = ac0.x + ac0.y + ac0.z + ac0.w;
    float v1 = ac1.x + ac1.y + ac1.z + ac1.w;
    float v2 = ac2.x + ac2.y + ac2.z + ac2.w;
    float v3 = ac3.x + ac3.y + ac3.z + ac3.w;
    float* oe = OutV + (size_t)e * 256;
    oe[(a0 + 0) * 16 + b] = v0;
    oe[(a0 + 1) * 16 + b] = v1;
    oe[(a0 + 2) * 16 + b] = v2;
    oe[(a0 + 3) * 16 + b] = v3;
    sC[w][b][a0 + 0] = v0;
    sC[w][b][a0 + 1] = v1;
    sC[w][b][a0 + 2] = v2;
    sC[w][b][a0 + 3] = v3;
    __syncthreads();
    int rr = lane >> 2, cc = (lane & 3) * 4;
    float4 t4 = { sC[w][rr][cc], sC[w][rr][cc + 1], sC[w][rr][cc + 2], sC[w][rr][cc + 3] };
    *(float4*)(OutV + (size_t)re * 256 + lane * 4) = t4;
}

// ---------------------------------------------------------------------------
// BP (R22 — unchanged: per-node normalizer, lane-0 finish, float2 fusion).
// ---------------------------------------------------------------------------
__global__ __launch_bounds__(704) void bp_kernel(
    const float* __restrict__ FV, const float* __restrict__ UV,
    const float* __restrict__ HFL, const float* __restrict__ Wcls,
    const float* __restrict__ bcls, const float* __restrict__ gum,
    const float* __restrict__ IFF, const float* __restrict__ IUU,
    float* __restrict__ out)
{
    int g = blockIdx.x, tid = threadIdx.x;
    __shared__ __align__(16) float fvs[EPG * 256];   // 135.2 KB: fv then E
    __shared__ __align__(16) float2 MU[EPG][16];     // {msg, umsg} 16.9 KB
    __shared__ __align__(16) float2 AU[NPG][16];     // {Asum, Usum}
    __shared__ __align__(16) float2 IU[NPG][16];     // {iff, iuu}
    __shared__ __align__(16) float2 gGU[44][16];     // {G, U} broadcast
    __shared__ float AUmax[NPG];
    __shared__ float fls[EPG];

    for (int i = tid; i < EPG * 16; i += 704)
        (&MU[0][0])[i] = make_float2(0.f, 0.f);
    if (tid < NPG * 16) {
        float fi = IFF[g * NPG * 16 + tid];
        float ui = IUU[g * NPG * 16 + tid];
        (&IU[0][0])[tid] = make_float2(fi, ui);
        (&AU[0][0])[tid] = make_float2(fi, ui);
        float m = fi;
        m = fmaxf(m, __shfl_xor(m, 1));
        m = fmaxf(m, __shfl_xor(m, 2));
        m = fmaxf(m, __shfl_xor(m, 4));
        m = fmaxf(m, __shfl_xor(m, 8));
        if ((tid & 15) == 0) AUmax[tid >> 4] = m;
    }
    // flags fold (same arithmetic order as original flags_kernel — exact)
    if (tid < EPG) {
        int el = tid, rel = rev_local(el);
        int e = g * EPG + el, re = g * EPG + rel;
        float l0 = bcls[0], l1 = bcls[1];
        const float* ha = HFL + (size_t)e * 32;
        const float* hb = HFL + (size_t)re * 32;
#pragma unroll
        for (int j = 0; j < 32; ++j) {
            float pp = ha[j] * hb[j];
            l0 += pp * Wcls[j * 2 + 0];
            l1 += pp * Wcls[j * 2 + 1];
        }
        int mn = min(e, re);
        l0 += gum[(size_t)mn * 2 + 0];
        l1 += gum[(size_t)mn * 2 + 1];
        fls[el] = (l0 >= l1) ? 1.0f : 0.0f;
    }

    // ---- stage FV into LDS, swizzled: word(e,a,qq) = e*256 + a*16 +
    //      ((qq ^ ((a>>1)&3))<<2).
    const float* fvg = FV + (size_t)g * EPG * 256;
    const float* uvg = UV + (size_t)g * EPG * 256;
    for (int t4 = tid; t4 < EPG * 64; t4 += 704) {
        float4 v = *(const float4*)(fvg + (size_t)t4 * 4);
        int e = t4 >> 6, rem = t4 & 63;
        int aa = rem >> 2, qq = rem & 3;
        int w = e * 256 + aa * 16 + ((qq ^ ((aa >> 1) & 3)) << 2);
        *(float4*)&fvs[w] = v;
    }

    int w44 = tid >> 4, a = tid & 15;
    int bl = (tid & 63) & 48;              // group base lane within wave
    int e0 = w44,      s0 = e0 / 11, r0 = rev_local(e0);
    int e1 = 44 + w44, s1 = e1 / 11, r1 = rev_local(e1);
    int e2 = 88 + w44, s2 = e2 / 11, r2 = rev_local(e2);

    int xr = (a >> 1) & 3;
    int sl0 = ((0 ^ xr) << 2), sl1 = ((1 ^ xr) << 2);
    int sl2 = ((2 ^ xr) << 2), sl3 = ((3 ^ xr) << 2);
    int fb0 = e0 * 256 + a * 16;
    int fb1 = e1 * 256 + a * 16;
    int fb2 = e2 * 256 + a * 16;

    const float* ur0 = uvg + (size_t)e0 * 256 + a * 16;
    const float* ur1 = uvg + (size_t)e1 * 256 + a * 16;
    const float* ur2 = uvg + (size_t)e2 * 256 + a * 16;

    __syncthreads();
    float fl0 = fls[e0], fl1 = fls[e1], fl2 = fls[e2];

    // ---- in-place transform: row (e,a) of fvs: fv -> E = exp(fv - fvmax).
    auto xform = [&](int fbase) -> float {
        float4 a0 = *(const float4*)&fvs[fbase + sl0];
        float4 a1 = *(const float4*)&fvs[fbase + sl1];
        float4 a2 = *(const float4*)&fvs[fbase + sl2];
        float4 a3 = *(const float4*)&fvs[fbase + sl3];
        float mx = fmaxf(fmaxf(fmaxf(a0.x, a0.y), fmaxf(a0.z, a0.w)),
                         fmaxf(fmaxf(a1.x, a1.y), fmaxf(a1.z, a1.w)));
        mx = fmaxf(mx, fmaxf(fmaxf(fmaxf(a2.x, a2.y), fmaxf(a2.z, a2.w)),
                             fmaxf(fmaxf(a3.x, a3.y), fmaxf(a3.z, a3.w))));
        a0.x = __expf(a0.x - mx); a0.y = __expf(a0.y - mx);
        a0.z = __expf(a0.z - mx); a0.w = __expf(a0.w - mx);
        a1.x = __expf(a1.x - mx); a1.y = __expf(a1.y - mx);
        a1.z = __expf(a1.z - mx); a1.w = __expf(a1.w - mx);
        a2.x = __expf(a2.x - mx); a2.y = __expf(a2.y - mx);
        a2.z = __expf(a2.z - mx); a2.w = __expf(a2.w - mx);
        a3.x = __expf(a3.x - mx); a3.y = __expf(a3.y - mx);
        a3.z = __expf(a3.z - mx); a3.w = __expf(a3.w - mx);
        *(float4*)&fvs[fbase + sl0] = a0;
        *(float4*)&fvs[fbase + sl1] = a1;
        *(float4*)&fvs[fbase + sl2] = a2;
        *(float4*)&fvs[fbase + sl3] = a3;
        return mx;
    };
    float fvm0 = xform(fb0);
    float fvm1 = xform(fb1);
    float fvm2 = xform(fb2);

    // edge core (factored): lane a owns b-slot a of the edge's shared agg.
    // Normalizer is the per-node AUmax (precomputed) — no per-edge shfl.
    auto edge_core = [&](int s, int re, int fbase, float fvm,
                         float4 uva, float4 uvb, float4 uvc, float4 uvd,
                         float& lse_o, float& unv_o) {
        float2 au = AU[s][a];
        float2 mu = MU[re][a];
        float aggA  = au.x - mu.x;
        float uaggA = au.y - mu.y;
        float nrm = AUmax[s];
        gGU[w44][a] = make_float2(__expf(aggA - nrm), uaggA);
        // same-wave LDS RAW: in-order DS + compiler lgkmcnt make this safe.
        float4 q0 = *(const float4*)&gGU[w44][0];
        float4 q1 = *(const float4*)&gGU[w44][2];
        float4 q2 = *(const float4*)&gGU[w44][4];
        float4 q3 = *(const float4*)&gGU[w44][6];
        float4 q4 = *(const float4*)&gGU[w44][8];
        float4 q5 = *(const float4*)&gGU[w44][10];
        float4 q6 = *(const float4*)&gGU[w44][12];
        float4 q7 = *(const float4*)&gGU[w44][14];
        float4 E0 = *(const float4*)&fvs[fbase + sl0];
        float4 E1 = *(const float4*)&fvs[fbase + sl1];
        float4 E2 = *(const float4*)&fvs[fbase + sl2];
        float4 E3 = *(const float4*)&fvs[fbase + sl3];
        float p0  = E0.x * q0.x, p1  = E0.y * q0.z;
        float p2  = E0.z * q1.x, p3  = E0.w * q1.z;
        float p4  = E1.x * q2.x, p5  = E1.y * q2.z;
        float p6  = E1.z * q3.x, p7  = E1.w * q3.z;
        float p8  = E2.x * q4.x, p9  = E2.y * q4.z;
        float p10 = E2.z * q5.x, p11 = E2.w * q5.z;
        float p12 = E3.x * q6.x, p13 = E3.y * q6.z;
        float p14 = E3.z * q7.x, p15 = E3.w * q7.z;
        float S = (((p0 + p1) + (p2 + p3)) + ((p4 + p5) + (p6 + p7)))
                + (((p8 + p9) + (p10 + p11)) + ((p12 + p13) + (p14 + p15)));
        float n0  = (uva.x + q0.y) * p0,  n1  = (uva.y + q0.w) * p1;
        float n2  = (uva.z + q1.y) * p2,  n3  = (uva.w + q1.w) * p3;
        float n4  = (uvb.x + q2.y) * p4,  n5  = (uvb.y + q2.w) * p5;
        float n6  = (uvb.z + q3.y) * p6,  n7  = (uvb.w + q3.w) * p7;
        float n8  = (uvc.x + q4.y) * p8,  n9  = (uvc.y + q4.w) * p9;
        float n10 = (uvc.z + q5.y) * p10, n11 = (uvc.w + q5.w) * p11;
        float n12 = (uvd.x + q6.y) * p12, n13 = (uvd.y + q6.w) * p13;
        float n14 = (uvd.z + q7.y) * p14, n15 = (uvd.w + q7.w) * p15;
        float num = (((n0 + n1) + (n2 + n3)) + ((n4 + n5) + (n6 + n7)))
                  + (((n8 + n9) + (n10 + n11)) + ((n12 + n13) + (n14 + n15)));
        S = fmaxf(S, 1e-37f);
        lse_o = (fvm + nrm) + __logf(S);
        unv_o = num / S;
    };

    for (int it = 0; it < NPG - 1; ++it) {
        // uv reloads issued at iteration top; latency hides under DS chain.
        float4 u0q0 = *(const float4*)(ur0 + 0),  u0q1 = *(const float4*)(ur0 + 4);
        float4 u0q2 = *(const float4*)(ur0 + 8),  u0q3 = *(const float4*)(ur0 + 12);
        float4 u1q0 = *(const float4*)(ur1 + 0),  u1q1 = *(const float4*)(ur1 + 4);
        float4 u1q2 = *(const float4*)(ur1 + 8),  u1q3 = *(const float4*)(ur1 + 12);
        float4 u2q0 = *(const float4*)(ur2 + 0),  u2q1 = *(const float4*)(ur2 + 4);
        float4 u2q2 = *(const float4*)(ur2 + 8),  u2q3 = *(const float4*)(ur2 + 12);

        float lse0, unv0, lse1, unv1, lse2, unv2;
        edge_core(s0, r0, fb0, fvm0, u0q0, u0q1, u0q2, u0q3, lse0, unv0);
        edge_core(s1, r1, fb1, fvm1, u1q0, u1q1, u1q2, u1q3, lse1, unv1);
        edge_core(s2, r2, fb2, fvm2, u2q0, u2q1, u2q2, u2q3, lse2, unv2);
        // finish: normalize by the group's lane-0 lse (1 shfl, per-edge-
        // uniform shift -> cancels exactly next iteration).
        float nm0 = (lse0 - __shfl(lse0, bl)) * fl0;
        float nm1 = (lse1 - __shfl(lse1, bl)) * fl1;
        float nm2 = (lse2 - __shfl(lse2, bl)) * fl2;
        float nu0 = unv0 * fl0, nu1 = unv1 * fl1, nu2 = unv2 * fl2;
        __syncthreads();            // all reads of MU complete
        MU[e0][a] = make_float2(nm0, nu0);
        MU[e1][a] = make_float2(nm1, nu1);
        MU[e2][a] = make_float2(nm2, nu2);
        __syncthreads();            // writes visible to aggregation
        if (tid < NPG * 16) {
            int n = tid >> 4, aa = tid & 15;
            float sm = 0.f, su = 0.f;
#pragma unroll
            for (int s = 0; s < NPG; ++s) {
                if (s == n) continue;
                int le = s * 11 + (n < s ? n : n - 1);
                float2 v = MU[le][aa];
                sm += v.x;
                su += v.y;
            }
            float2 iu = IU[n][aa];
            float as = sm + iu.x;
            AU[n][aa] = make_float2(as, su + iu.y);
            float m = as;
            m = fmaxf(m, __shfl_xor(m, 1));
            m = fmaxf(m, __shfl_xor(m, 2));
            m = fmaxf(m, __shfl_xor(m, 4));
            m = fmaxf(m, __shfl_xor(m, 8));
            if (aa == 0) AUmax[n] = m;
        }
        __syncthreads();            // AU + AUmax ready for next iteration
    }

    // ---- final (12th) iteration: only umsg for edges into node 0 ----
    {
        float nu0 = 0.f, nu1 = 0.f, nu2 = 0.f;
        bool own = ((w44 % 11) == 0);
        if (own) {
            float lse, unv;
            if (e0 != 0) {
                float4 q0 = *(const float4*)(ur0 + 0), q1 = *(const float4*)(ur0 + 4);
                float4 q2 = *(const float4*)(ur0 + 8), q3 = *(const float4*)(ur0 + 12);
                edge_core(s0, r0, fb0, fvm0, q0, q1, q2, q3, lse, unv);
                nu0 = unv * fl0;
            }
            {
                float4 q0 = *(const float4*)(ur1 + 0), q1 = *(const float4*)(ur1 + 4);
                float4 q2 = *(const float4*)(ur1 + 8), q3 = *(const float4*)(ur1 + 12);
                edge_core(s1, r1, fb1, fvm1, q0, q1, q2, q3, lse, unv);
                nu1 = unv * fl1;
            }
            {
                float4 q0 = *(const float4*)(ur2 + 0), q1 = *(const float4*)(ur2 + 4);
                float4 q2 = *(const float4*)(ur2 + 8), q3 = *(const float4*)(ur2 + 12);
                edge_core(s2, r2, fb2, fvm2, q0, q1, q2, q3, lse, unv);
                nu2 = unv * fl2;
            }
            (void)lse;
        }
        __syncthreads();            // all reads of MU complete
        if (own) {
            if (e0 != 0) MU[e0][a] = make_float2(0.f, nu0);
            MU[e1][a] = make_float2(0.f, nu1);
            MU[e2][a] = make_float2(0.f, nu2);
        }
        __syncthreads();
        if (tid < 16) {
            float su = 0.f;
#pragma unroll
            for (int s = 1; s < NPG; ++s) su += MU[s * 11][tid].y;
            out[g * 16 + tid] = su + IU[0][tid].y;
        }
    }
}

// ---------------------------------------------------------------------------
extern "C" void kernel_launch(void* const* d_in, const int* in_sizes, int n_in,
                              void* d_out, int out_size, void* d_ws, size_t ws_size,
                              hipStream_t stream) {
    const float* edge_feats  = (const float*)d_in[0];
    const float* node_feats  = (const float*)d_in[1];
    const float* graph_feats = (const float*)d_in[2];
    // d_in[3] edge_feat_reflected: unused (== edge_feats[rev])
    // d_in[4] src, d_in[5] dst, d_in[6] idx_revs: unused (analytic graph structure)
    const float* gumbel      = (const float*)d_in[7];
    const float* W_jf        = (const float*)d_in[8];
    const float* b_jf        = (const float*)d_in[9];
    const float* W_if        = (const float*)d_in[10];
    const float* b_if        = (const float*)d_in[11];
    const float* W_ju        = (const float*)d_in[12];
    const float* b_ju        = (const float*)d_in[13];
    const float* W_iu        = (const float*)d_in[14];
    const float* b_iu        = (const float*)d_in[15];
    const float* W_fl        = (const float*)d_in[16];
    const float* b_fl        = (const float*)d_in[17];
    const float* W_cls       = (const float*)d_in[18];
    const float* b_cls       = (const float*)d_in[19];
    float* out = (float*)d_out;          // reference output dtype is float32
    (void)in_sizes; (void)n_in; (void)out_size; (void)ws_size;

    size_t off = 0;
    char* base = (char*)d_ws;
    auto alloc = [&](size_t bytes) {
        void* p = base + off;
        off += (bytes + 255) & ~(size_t)255;
        return p;
    };
    ushort_t* XeS   = (ushort_t*)alloc((size_t)E_TOT * KD2 * 2);  // 13.0 MB
    ushort_t* WtJFs = (ushort_t*)alloc((size_t)NJ * KD2 * 2);     // 0.39 MB
    ushort_t* WtJUs = (ushort_t*)alloc((size_t)NJ * KD2 * 2);     // 0.39 MB
    float*    CGp   = (float*)   alloc((size_t)2 * 128 * NJ * 4); // 0.52 MB
    float*    HFL   = (float*)   alloc((size_t)E_TOT * 32 * 4);   // 2.16 MB
    float*    IFFp  = (float*)   alloc((size_t)NT * 16 * 4);
    float*    IUUp  = (float*)   alloc((size_t)NT * 16 * 4);
    float*    H2    = (float*)   alloc((size_t)E_TOT * NJ * 2 * 4); // 69.2 MB
    float*    FVUV  = (float*)   alloc((size_t)E_TOT * 512 * 4);    // 34.6 MB
    float* FVv = FVUV;
    float* UVv = FVUV + (size_t)E_TOT * 256;

    const int prep_blocks = 32 + 1056 + 512 + 192 + 264;   // 2056 (hfl merged)

    prep_kernel<<<prep_blocks, 256, 0, stream>>>(
        W_jf, W_ju, edge_feats, graph_feats, b_jf, b_ju, node_feats,
        W_if, b_if, W_iu, b_iu, W_fl, b_fl,
        WtJFs, WtJUs, XeS, CGp, IFFp, IUUp, HFL);
    gemm_kernel<<<1088, 256, 0, stream>>>(XeS, WtJFs, WtJUs, H2);
    pair_kernel<<<dim3(NCAN / 4, 2), 256, 0, stream>>>(H2, CGp, FVUV);
    bp_kernel<<<BGR, 704, 0, stream>>>(FVv, UVv, HFL, W_cls, b_cls, gumbel,
                                       IFFp, IUUp, out);
}